// Round 12
// baseline (431.185 us; speedup 1.0000x reference)
//
#include <hip/hip_runtime.h>

#define BNSC 0.99999500003749963f

typedef _Float16 f16;
typedef _Float16 f16x8 __attribute__((ext_vector_type(8)));
typedef float    f32x4 __attribute__((ext_vector_type(4)));

static __device__ __forceinline__ float lrelu_f(float a) { return a >= 0.0f ? a : 0.1f * a; }

// XCD-locality swizzle (bijective; identity when (GX*GZ)%8 != 0).
static __device__ __forceinline__ void xcd_swz(int& bx, int& by, int& bz) {
    const int GX = gridDim.x, GY = gridDim.y, GZ = gridDim.z;
    if (((GX * GZ) & 7) == 0) {
        const int lin = blockIdx.x + GX * (blockIdx.y + GY * blockIdx.z);
        const int xcd = lin & 7;
        const int rest = lin >> 3;
        by = rest % GY;
        const int g = (rest / GY) * 8 + xcd;
        bx = g % GX;
        bz = g / GX;
    } else {
        bx = blockIdx.x; by = blockIdx.y; bz = blockIdx.z;
    }
}

// ============ weight prep: fp32 -> f16 copies (+ tcn permute (m,k,tau)->(tau,m,k)) ============
__global__ __launch_bounds__(256) void prep_w_k(
    const float* __restrict__ Wins, const float* __restrict__ Wouts,
    const float* __restrict__ Wffs, const float* __restrict__ Wint,
    const float* __restrict__ Woutt, const float* __restrict__ Wfft,
    const float* __restrict__ Wtcn, f16* __restrict__ dst)
{
    int i = blockIdx.x * 256 + threadIdx.x;
    int o = 0;
    if (i < 49152) { dst[o + i] = (f16)Wins[i];  return; } i -= 49152; o += 49152;
    if (i < 49152) { dst[o + i] = (f16)Wouts[i]; return; } i -= 49152; o += 49152;
    if (i < 16384) { dst[o + i] = (f16)Wffs[i];  return; } i -= 16384; o += 16384;
    if (i < 65536) { dst[o + i] = (f16)Wint[i];  return; } i -= 65536; o += 65536;
    if (i < 65536) { dst[o + i] = (f16)Woutt[i]; return; } i -= 65536; o += 65536;
    if (i < 16384) { dst[o + i] = (f16)Wfft[i];  return; } i -= 16384; o += 16384;
    if (i < 114688) {
        int tau = i / 16384, rem = i - tau * 16384;      // rem = m*128 + k
        dst[o + i] = (f16)Wtcn[(size_t)rem * 7 + tau];
    }
}

// ============ x (n,128,1600) fp32 -> xT (n,1600,128) f16  AND xBp (n,128,64,32) f16 ============
__global__ __launch_bounds__(256) void x_to_T_k(const float* __restrict__ x,
                                                f16* __restrict__ xT, f16* __restrict__ xBp)
{
    __shared__ float L[64 * 68];
    const int n = blockIdx.z, tv0 = blockIdx.x * 64, c0 = blockIdx.y * 64;
    const int tid = threadIdx.x;
    const int cc = tid >> 4, tv4 = (tid & 15) * 4;
    f16* xBn = xBp + (size_t)n * 262144;
    #pragma unroll
    for (int p = 0; p < 4; ++p) {
        const int c = cc + p * 16;
        float4 v = *(const float4*)&x[((size_t)n * 128 + c0 + c) * 1600 + tv0 + tv4];
        *(float4*)&L[c * 68 + tv4] = v;
        const float vv[4] = {v.x, v.y, v.z, v.w};
        #pragma unroll
        for (int e = 0; e < 4; ++e) {
            const int tvg = tv0 + tv4 + e;
            const int t = tvg / 25, u = tvg - t * 25;
            xBn[(size_t)(c0 + c) * 2048 + t * 32 + u] = (f16)vv[e];
        }
    }
    __syncthreads();
    const int tv = tid & 63, cb = (tid >> 6) * 16;
    f16x8 o0, o1;
    #pragma unroll
    for (int i = 0; i < 8; ++i) o0[i] = (f16)L[(cb + i) * 68 + tv];
    #pragma unroll
    for (int i = 0; i < 8; ++i) o1[i] = (f16)L[(cb + 8 + i) * 68 + tv];
    f16* dst = &xT[((size_t)n * 1600 + tv0 + tv) * 128 + c0 + cb];
    *(f16x8*)dst = o0;
    *(f16x8*)(dst + 8) = o1;
}

// ============ outT (n,1600,128) f16 -> out (n,128,1600) fp32 ============
__global__ __launch_bounds__(256) void T_to_out_k(const f16* __restrict__ oT, float* __restrict__ out)
{
    __shared__ float L[128 * 69];
    const int n = blockIdx.z, tv0 = blockIdx.x * 64;
    const int tid = threadIdx.x;
    #pragma unroll
    for (int p = 0; p < 4; ++p) {
        int idx = tid + p * 256;
        int tv = idx >> 4, c8 = (idx & 15) * 8;
        f16x8 v = *(const f16x8*)&oT[((size_t)n * 1600 + tv0 + tv) * 128 + c8];
        #pragma unroll
        for (int i = 0; i < 8; ++i) L[(c8 + i) * 69 + tv] = (float)v[i];
    }
    __syncthreads();
    const int c = tid >> 1, tvb = (tid & 1) * 32;
    #pragma unroll
    for (int j = 0; j < 8; ++j) {
        float4 o;
        o.x = L[c * 69 + tvb + j * 4 + 0];
        o.y = L[c * 69 + tvb + j * 4 + 1];
        o.z = L[c * 69 + tvb + j * 4 + 2];
        o.w = L[c * 69 + tvb + j * 4 + 3];
        *(float4*)&out[((size_t)n * 128 + c) * 1600 + tv0 + tvb + j * 4] = o;
    }
}

// ============ T-layout MFMA GEMM (64x64 tile, BK=128) with vectorized epilogue ========
template<int EPI>
__global__ __launch_bounds__(256) void gemm_t_k(
    const f16* __restrict__ A, const f16* __restrict__ W,
    const float* __restrict__ bias,
    const float* __restrict__ g, const float* __restrict__ be,
    const f16* __restrict__ res, f16* __restrict__ out,
    int K, int M)
{
    __shared__ __align__(16) char smem[34816];
    f16* As = (f16*)smem;
    f16* Bs = (f16*)(smem + 17408);
    float* Ss = (float*)smem;
    int bx, by, bz;
    xcd_swz(bx, by, bz);
    const int n = bz, tv0 = bx * 64, m0 = by * 64;
    const int tid = threadIdx.x;
    const int w = tid >> 6, lane = tid & 63;
    const int wr = w >> 1, wc = w & 1;
    const int lg = lane >> 4, lr = lane & 15;
    const int srow = tid >> 3, scol = (tid & 7) * 16;
    const f16* An = A + (size_t)n * 1600 * K;
    f32x4 acc[2][2] = {};

    for (int k0 = 0; k0 < K; k0 += 128) {
        const f16* ar0 = An + (size_t)(tv0 + srow) * K + k0 + scol;
        const f16* ar1 = An + (size_t)(tv0 + srow + 32) * K + k0 + scol;
        const f16* br0 = W + (size_t)(m0 + srow) * K + k0 + scol;
        const f16* br1 = W + (size_t)(m0 + srow + 32) * K + k0 + scol;
        uint4 a0 = *(const uint4*)ar0, a1 = *(const uint4*)(ar0 + 8);
        uint4 a2 = *(const uint4*)ar1, a3 = *(const uint4*)(ar1 + 8);
        uint4 b0 = *(const uint4*)br0, b1 = *(const uint4*)(br0 + 8);
        uint4 b2 = *(const uint4*)br1, b3 = *(const uint4*)(br1 + 8);
        __syncthreads();
        *(uint4*)&As[srow * 136 + scol] = a0;
        *(uint4*)&As[srow * 136 + scol + 8] = a1;
        *(uint4*)&As[(srow + 32) * 136 + scol] = a2;
        *(uint4*)&As[(srow + 32) * 136 + scol + 8] = a3;
        *(uint4*)&Bs[srow * 136 + scol] = b0;
        *(uint4*)&Bs[srow * 136 + scol + 8] = b1;
        *(uint4*)&Bs[(srow + 32) * 136 + scol] = b2;
        *(uint4*)&Bs[(srow + 32) * 136 + scol + 8] = b3;
        __syncthreads();
        #pragma unroll
        for (int kb = 0; kb < 128; kb += 32) {
            f16x8 af0 = *(const f16x8*)&As[(wr * 32 + lr) * 136 + kb + lg * 8];
            f16x8 af1 = *(const f16x8*)&As[(wr * 32 + 16 + lr) * 136 + kb + lg * 8];
            f16x8 bf0 = *(const f16x8*)&Bs[(wc * 32 + lr) * 136 + kb + lg * 8];
            f16x8 bf1 = *(const f16x8*)&Bs[(wc * 32 + 16 + lr) * 136 + kb + lg * 8];
            acc[0][0] = __builtin_amdgcn_mfma_f32_16x16x32_f16(af0, bf0, acc[0][0], 0, 0, 0);
            acc[0][1] = __builtin_amdgcn_mfma_f32_16x16x32_f16(af0, bf1, acc[0][1], 0, 0, 0);
            acc[1][0] = __builtin_amdgcn_mfma_f32_16x16x32_f16(af1, bf0, acc[1][0], 0, 0, 0);
            acc[1][1] = __builtin_amdgcn_mfma_f32_16x16x32_f16(af1, bf1, acc[1][1], 0, 0, 0);
        }
        __syncthreads();
    }
    #pragma unroll
    for (int fi = 0; fi < 2; ++fi)
        #pragma unroll
        for (int fj = 0; fj < 2; ++fj)
            #pragma unroll
            for (int rr = 0; rr < 4; ++rr)
                Ss[(wr * 32 + fi * 16 + lg * 4 + rr) * 68 + wc * 32 + fj * 16 + lr] = acc[fi][fj][rr];
    __syncthreads();
    const int tvl = tid >> 2, mq = (tid & 3) * 16;
    const int tv = tv0 + tvl;
    const int m  = m0 + mq;
    float vals[16];
    #pragma unroll
    for (int j = 0; j < 4; ++j)
        *(float4*)&vals[j * 4] = *(const float4*)&Ss[tvl * 68 + mq + j * 4];
    float bi[16];
    #pragma unroll
    for (int j = 0; j < 4; ++j) *(float4*)&bi[j * 4] = *(const float4*)&bias[m + j * 4];
    if (EPI == 1) {
        float gg[16], bb[16];
        #pragma unroll
        for (int j = 0; j < 4; ++j) {
            *(float4*)&gg[j * 4] = *(const float4*)&g[m + j * 4];
            *(float4*)&bb[j * 4] = *(const float4*)&be[m + j * 4];
        }
        const f16* rp = res + ((size_t)n * 1600 + tv) * M + m;
        f16x8 r0 = *(const f16x8*)rp;
        f16x8 r1 = *(const f16x8*)(rp + 8);
        #pragma unroll
        for (int j = 0; j < 16; ++j) {
            float r = (float)((j < 8) ? r0[j & 7] : r1[j & 7]);
            vals[j] = lrelu_f(r + (vals[j] + bi[j]) * (gg[j] * BNSC) + bb[j]);
        }
    } else {
        #pragma unroll
        for (int j = 0; j < 16; ++j) vals[j] += bi[j];
    }
    f16x8 o0, o1;
    #pragma unroll
    for (int j = 0; j < 8; ++j) { o0[j] = (f16)vals[j]; o1[j] = (f16)vals[8 + j]; }
    f16* op = out + ((size_t)n * 1600 + tv) * M + m;
    *(f16x8*)op = o0;
    *(f16x8*)(op + 8) = o1;
}

// ============ FUSED dual GEMM: out = epi2(W2 @ epi1(W1 @ Ain)), M1=M2=K2=128 ============
// epi_i(v) = lrelu(res + (v + b_i)*g_i*BNSC + be_i); res shared by both epilogues.
// Intermediate y-tile (64x128) lives only in LDS.
template<int K1>
__global__ __launch_bounds__(256) void fused2_k(
    const f16* __restrict__ Ain,   // (64,1600,K1)
    const f16* __restrict__ W1,    // (128,K1)
    const float* __restrict__ b1, const float* __restrict__ g1, const float* __restrict__ be1,
    const f16* __restrict__ W2,    // (128,128)
    const float* __restrict__ b2, const float* __restrict__ g2, const float* __restrict__ be2,
    const f16* __restrict__ res,   // (64,1600,128)
    f16* __restrict__ out)         // (64,1600,128)
{
    __shared__ __align__(16) char smem[35840];
    f16* As1  = (f16*)smem;                 // 64 x 72
    f16* Bs1  = (f16*)(smem + 9216);        // 128 x 72
    float* Ss = (float*)smem;               // 64 x 132 f32 (33792 B)
    f16* Ys   = (f16*)smem;                 // 64 x 136 (17408 B)
    f16* Bs2  = (f16*)(smem + 17408);       // 128 x 72 (18432 B)
    int bx, by, bz;
    xcd_swz(bx, by, bz);
    const int n = bz, tv0 = bx * 64;
    const int tid = threadIdx.x;
    const int w = tid >> 6, lane = tid & 63;
    const int wr = w >> 1, wc = w & 1;
    const int lg = lane >> 4, lr = lane & 15;
    const int srow = tid >> 3, sc = (tid & 7) * 8;
    const f16* An = Ain + (size_t)n * 1600 * K1;
    const f16* rn = res + ((size_t)n * 1600 + tv0) * 128;

    // ---- phase 1: 64x128 tile of gemm1 over K1 (BK=64) ----
    f32x4 acc[2][4] = {};
    for (int k0 = 0; k0 < K1; k0 += 64) {
        uint4 a0 = *(const uint4*)(An + (size_t)(tv0 + srow) * K1 + k0 + sc);
        uint4 a1 = *(const uint4*)(An + (size_t)(tv0 + srow + 32) * K1 + k0 + sc);
        uint4 w0 = *(const uint4*)(W1 + (size_t)srow * K1 + k0 + sc);
        uint4 w1v = *(const uint4*)(W1 + (size_t)(srow + 32) * K1 + k0 + sc);
        uint4 w2v = *(const uint4*)(W1 + (size_t)(srow + 64) * K1 + k0 + sc);
        uint4 w3v = *(const uint4*)(W1 + (size_t)(srow + 96) * K1 + k0 + sc);
        __syncthreads();
        *(uint4*)&As1[srow * 72 + sc] = a0;
        *(uint4*)&As1[(srow + 32) * 72 + sc] = a1;
        *(uint4*)&Bs1[srow * 72 + sc] = w0;
        *(uint4*)&Bs1[(srow + 32) * 72 + sc] = w1v;
        *(uint4*)&Bs1[(srow + 64) * 72 + sc] = w2v;
        *(uint4*)&Bs1[(srow + 96) * 72 + sc] = w3v;
        __syncthreads();
        #pragma unroll
        for (int kb = 0; kb < 64; kb += 32) {
            f16x8 af0 = *(const f16x8*)&As1[(wr * 32 + lr) * 72 + kb + lg * 8];
            f16x8 af1 = *(const f16x8*)&As1[(wr * 32 + 16 + lr) * 72 + kb + lg * 8];
            #pragma unroll
            for (int ft = 0; ft < 4; ++ft) {
                f16x8 bf = *(const f16x8*)&Bs1[(wc * 64 + ft * 16 + lr) * 72 + kb + lg * 8];
                acc[0][ft] = __builtin_amdgcn_mfma_f32_16x16x32_f16(af0, bf, acc[0][ft], 0, 0, 0);
                acc[1][ft] = __builtin_amdgcn_mfma_f32_16x16x32_f16(af1, bf, acc[1][ft], 0, 0, 0);
            }
        }
        __syncthreads();
    }
    // ---- epilogue 1 -> Ys (LDS only; y never hits HBM) ----
    #pragma unroll
    for (int fi = 0; fi < 2; ++fi)
        #pragma unroll
        for (int ft = 0; ft < 4; ++ft)
            #pragma unroll
            for (int rr = 0; rr < 4; ++rr)
                Ss[(wr * 32 + fi * 16 + lg * 4 + rr) * 132 + wc * 64 + ft * 16 + lr] = acc[fi][ft][rr];
    __syncthreads();
    const int tvl = tid >> 2, q4 = (tid & 3) * 16;
    f16x8 yh[4];
    #pragma unroll
    for (int mh = 0; mh < 2; ++mh) {
        const int mq = mh * 64 + q4;
        float vals[16], bb[16], gg[16], eb[16];
        #pragma unroll
        for (int j = 0; j < 4; ++j) {
            *(float4*)&vals[j * 4] = *(const float4*)&Ss[tvl * 132 + mq + j * 4];
            *(float4*)&bb[j * 4]   = *(const float4*)&b1[mq + j * 4];
            *(float4*)&gg[j * 4]   = *(const float4*)&g1[mq + j * 4];
            *(float4*)&eb[j * 4]   = *(const float4*)&be1[mq + j * 4];
        }
        const f16* rp = rn + (size_t)tvl * 128 + mq;
        f16x8 r0 = *(const f16x8*)rp, r1 = *(const f16x8*)(rp + 8);
        #pragma unroll
        for (int j = 0; j < 16; ++j) {
            float r = (float)((j < 8) ? r0[j & 7] : r1[j & 7]);
            vals[j] = lrelu_f(r + (vals[j] + bb[j]) * (gg[j] * BNSC) + eb[j]);
        }
        #pragma unroll
        for (int j = 0; j < 8; ++j) {
            yh[mh * 2][j]     = (f16)vals[j];
            yh[mh * 2 + 1][j] = (f16)vals[8 + j];
        }
    }
    __syncthreads();   // all Ss reads done before Ys (alias) writes
    *(f16x8*)&Ys[tvl * 136 + q4]          = yh[0];
    *(f16x8*)&Ys[tvl * 136 + q4 + 8]      = yh[1];
    *(f16x8*)&Ys[tvl * 136 + 64 + q4]     = yh[2];
    *(f16x8*)&Ys[tvl * 136 + 64 + q4 + 8] = yh[3];

    // ---- phase 2: gemm2 (K=128, BK=64), A = Ys ----
    f32x4 acc2[2][4] = {};
    for (int k2 = 0; k2 < 128; k2 += 64) {
        uint4 w0 = *(const uint4*)(W2 + (size_t)srow * 128 + k2 + sc);
        uint4 w1v = *(const uint4*)(W2 + (size_t)(srow + 32) * 128 + k2 + sc);
        uint4 w2v = *(const uint4*)(W2 + (size_t)(srow + 64) * 128 + k2 + sc);
        uint4 w3v = *(const uint4*)(W2 + (size_t)(srow + 96) * 128 + k2 + sc);
        __syncthreads();   // covers Ys writes (iter 0) / prior MFMA Bs2 reads (iter 1)
        *(uint4*)&Bs2[srow * 72 + sc] = w0;
        *(uint4*)&Bs2[(srow + 32) * 72 + sc] = w1v;
        *(uint4*)&Bs2[(srow + 64) * 72 + sc] = w2v;
        *(uint4*)&Bs2[(srow + 96) * 72 + sc] = w3v;
        __syncthreads();
        #pragma unroll
        for (int kb = 0; kb < 64; kb += 32) {
            f16x8 af0 = *(const f16x8*)&Ys[(wr * 32 + lr) * 136 + k2 + kb + lg * 8];
            f16x8 af1 = *(const f16x8*)&Ys[(wr * 32 + 16 + lr) * 136 + k2 + kb + lg * 8];
            #pragma unroll
            for (int ft = 0; ft < 4; ++ft) {
                f16x8 bf = *(const f16x8*)&Bs2[(wc * 64 + ft * 16 + lr) * 72 + kb + lg * 8];
                acc2[0][ft] = __builtin_amdgcn_mfma_f32_16x16x32_f16(af0, bf, acc2[0][ft], 0, 0, 0);
                acc2[1][ft] = __builtin_amdgcn_mfma_f32_16x16x32_f16(af1, bf, acc2[1][ft], 0, 0, 0);
            }
        }
    }
    __syncthreads();
    // ---- epilogue 2 -> global out ----
    #pragma unroll
    for (int fi = 0; fi < 2; ++fi)
        #pragma unroll
        for (int ft = 0; ft < 4; ++ft)
            #pragma unroll
            for (int rr = 0; rr < 4; ++rr)
                Ss[(wr * 32 + fi * 16 + lg * 4 + rr) * 132 + wc * 64 + ft * 16 + lr] = acc2[fi][ft][rr];
    __syncthreads();
    f16* op = out + ((size_t)n * 1600 + tv0 + tvl) * 128;
    #pragma unroll
    for (int mh = 0; mh < 2; ++mh) {
        const int mq = mh * 64 + q4;
        float vals[16], bb[16], gg[16], eb[16];
        #pragma unroll
        for (int j = 0; j < 4; ++j) {
            *(float4*)&vals[j * 4] = *(const float4*)&Ss[tvl * 132 + mq + j * 4];
            *(float4*)&bb[j * 4]   = *(const float4*)&b2[mq + j * 4];
            *(float4*)&gg[j * 4]   = *(const float4*)&g2[mq + j * 4];
            *(float4*)&eb[j * 4]   = *(const float4*)&be2[mq + j * 4];
        }
        const f16* rp = rn + (size_t)tvl * 128 + mq;
        f16x8 r0 = *(const f16x8*)rp, r1 = *(const f16x8*)(rp + 8);
        #pragma unroll
        for (int j = 0; j < 16; ++j) {
            float r = (float)((j < 8) ? r0[j & 7] : r1[j & 7]);
            vals[j] = lrelu_f(r + (vals[j] + bb[j]) * (gg[j] * BNSC) + eb[j]);
        }
        f16x8 o0, o1;
        #pragma unroll
        for (int j = 0; j < 8; ++j) { o0[j] = (f16)vals[j]; o1[j] = (f16)vals[8 + j]; }
        *(f16x8*)(op + mq) = o0;
        *(f16x8*)(op + mq + 8) = o1;
    }
}

// ============ TCN (64x64 tile, BK=128 per tau) ============
__global__ __launch_bounds__(256) void tcn_T_k(
    const f16* __restrict__ z2T, const f16* __restrict__ W7,
    const float* __restrict__ bias, const float* __restrict__ g,
    const float* __restrict__ be, f16* __restrict__ outT)
{
    __shared__ __align__(16) char smem[34816];
    f16* As = (f16*)smem;
    f16* Bs = (f16*)(smem + 17408);
    float* Ss = (float*)smem;
    int bx, by, bz;
    xcd_swz(bx, by, bz);
    const int n = bz, tv0 = bx * 64, m0 = by * 64;
    const int tid = threadIdx.x;
    const int w = tid >> 6, lane = tid & 63;
    const int wr = w >> 1, wc = w & 1;
    const int lg = lane >> 4, lr = lane & 15;
    const int srow = tid >> 3, scol = (tid & 7) * 16;
    const f16* Zn = z2T + (size_t)n * 204800;
    f32x4 acc[2][2] = {};

    for (int tau = 0; tau < 7; ++tau) {
        const int shift = (tau - 3) * 25;
        const f16* Wt = W7 + tau * 16384;
        const int gr0 = tv0 + srow + shift;
        const int gr1 = gr0 + 32;
        uint4 a0 = make_uint4(0,0,0,0), a1 = a0, a2 = a0, a3 = a0;
        if (gr0 >= 0 && gr0 < 1600) {
            const f16* p = Zn + (size_t)gr0 * 128 + scol;
            a0 = *(const uint4*)p; a1 = *(const uint4*)(p + 8);
        }
        if (gr1 >= 0 && gr1 < 1600) {
            const f16* p = Zn + (size_t)gr1 * 128 + scol;
            a2 = *(const uint4*)p; a3 = *(const uint4*)(p + 8);
        }
        const f16* br0 = Wt + (size_t)(m0 + srow) * 128 + scol;
        const f16* br1 = Wt + (size_t)(m0 + srow + 32) * 128 + scol;
        uint4 b0 = *(const uint4*)br0, b1 = *(const uint4*)(br0 + 8);
        uint4 b2 = *(const uint4*)br1, b3 = *(const uint4*)(br1 + 8);
        __syncthreads();
        *(uint4*)&As[srow * 136 + scol] = a0;
        *(uint4*)&As[srow * 136 + scol + 8] = a1;
        *(uint4*)&As[(srow + 32) * 136 + scol] = a2;
        *(uint4*)&As[(srow + 32) * 136 + scol + 8] = a3;
        *(uint4*)&Bs[srow * 136 + scol] = b0;
        *(uint4*)&Bs[srow * 136 + scol + 8] = b1;
        *(uint4*)&Bs[(srow + 32) * 136 + scol] = b2;
        *(uint4*)&Bs[(srow + 32) * 136 + scol + 8] = b3;
        __syncthreads();
        #pragma unroll
        for (int kb = 0; kb < 128; kb += 32) {
            f16x8 af0 = *(const f16x8*)&As[(wr * 32 + lr) * 136 + kb + lg * 8];
            f16x8 af1 = *(const f16x8*)&As[(wr * 32 + 16 + lr) * 136 + kb + lg * 8];
            f16x8 bf0 = *(const f16x8*)&Bs[(wc * 32 + lr) * 136 + kb + lg * 8];
            f16x8 bf1 = *(const f16x8*)&Bs[(wc * 32 + 16 + lr) * 136 + kb + lg * 8];
            acc[0][0] = __builtin_amdgcn_mfma_f32_16x16x32_f16(af0, bf0, acc[0][0], 0, 0, 0);
            acc[0][1] = __builtin_amdgcn_mfma_f32_16x16x32_f16(af0, bf1, acc[0][1], 0, 0, 0);
            acc[1][0] = __builtin_amdgcn_mfma_f32_16x16x32_f16(af1, bf0, acc[1][0], 0, 0, 0);
            acc[1][1] = __builtin_amdgcn_mfma_f32_16x16x32_f16(af1, bf1, acc[1][1], 0, 0, 0);
        }
        __syncthreads();
    }
    #pragma unroll
    for (int fi = 0; fi < 2; ++fi)
        #pragma unroll
        for (int fj = 0; fj < 2; ++fj)
            #pragma unroll
            for (int rr = 0; rr < 4; ++rr)
                Ss[(wr * 32 + fi * 16 + lg * 4 + rr) * 68 + wc * 32 + fj * 16 + lr] = acc[fi][fj][rr];
    __syncthreads();
    const int tvl = tid >> 2, mq = (tid & 3) * 16;
    const int tv = tv0 + tvl;
    const int m  = m0 + mq;
    float vals[16], bi[16], gg[16], bb[16];
    #pragma unroll
    for (int j = 0; j < 4; ++j) {
        *(float4*)&vals[j * 4] = *(const float4*)&Ss[tvl * 68 + mq + j * 4];
        *(float4*)&bi[j * 4]   = *(const float4*)&bias[m + j * 4];
        *(float4*)&gg[j * 4]   = *(const float4*)&g[m + j * 4];
        *(float4*)&bb[j * 4]   = *(const float4*)&be[m + j * 4];
    }
    const f16* rp = Zn + (size_t)tv * 128 + m;
    f16x8 r0 = *(const f16x8*)rp;
    f16x8 r1 = *(const f16x8*)(rp + 8);
    #pragma unroll
    for (int j = 0; j < 16; ++j) {
        float r = (float)((j < 8) ? r0[j & 7] : r1[j & 7]);
        vals[j] = lrelu_f(r + (vals[j] + bi[j]) * (gg[j] * BNSC) + bb[j]);
    }
    f16x8 o0, o1;
    #pragma unroll
    for (int j = 0; j < 8; ++j) { o0[j] = (f16)vals[j]; o1[j] = (f16)vals[8 + j]; }
    f16* op = outT + ((size_t)n * 1600 + tv) * 128 + m;
    *(f16x8*)op = o0;
    *(f16x8*)(op + 8) = o1;
}

// ============ spatial scores via MFMA, t-chunked partials ============
__global__ __launch_bounds__(256) void att_s_mfma_k(
    const f16* __restrict__ QKT, float* __restrict__ P)
{
    __shared__ float Lred[4][1024];
    const int n = blockIdx.x / 24;
    const int rs = blockIdx.x % 24;
    const int s = rs >> 3, tc = rs & 7;
    const int tid = threadIdx.x;
    const int w = tid >> 6, lane = tid & 63;
    const int lg = lane >> 4, lr = lane & 15;
    const int qc = s * 64, kc = 192 + s * 64;
    const f16* Qn = QKT + (size_t)n * 1600 * 384;
    f32x4 acc[2][2] = {};

    #pragma unroll
    for (int tt = 0; tt < 2; ++tt) {
        const int t = tc * 8 + w * 2 + tt;
        const size_t rbase = (size_t)t * 25;
        #pragma unroll
        for (int kb = 0; kb < 2; ++kb) {
            f16x8 a[2] = {}, b[2] = {};
            #pragma unroll
            for (int rt = 0; rt < 2; ++rt) {
                const int u = rt * 16 + lr;
                if (u < 25) {
                    const f16* rp = Qn + (rbase + u) * 384;
                    a[rt] = *(const f16x8*)(rp + qc + kb * 32 + lg * 8);
                    b[rt] = *(const f16x8*)(rp + kc + kb * 32 + lg * 8);
                }
            }
            #pragma unroll
            for (int rt = 0; rt < 2; ++rt)
                #pragma unroll
                for (int ct = 0; ct < 2; ++ct)
                    acc[rt][ct] = __builtin_amdgcn_mfma_f32_16x16x32_f16(a[rt], b[ct], acc[rt][ct], 0, 0, 0);
        }
    }
    #pragma unroll
    for (int rt = 0; rt < 2; ++rt)
        #pragma unroll
        for (int ct = 0; ct < 2; ++ct)
            #pragma unroll
            for (int rr = 0; rr < 4; ++rr) {
                const int u = rt * 16 + lg * 4 + rr;
                const int v = ct * 16 + lr;
                Lred[w][u * 32 + v] = acc[rt][ct][rr];
            }
    __syncthreads();
    float* Pp = P + (((size_t)n * 3 + s) * 8 + tc) * 1024;
    for (int i = tid; i < 1024; i += 256)
        Pp[i] = Lred[0][i] + Lred[1][i] + Lred[2][i] + Lred[3][i];
}

// finalize: att[n,s,u,v] = tanh(sum_tc P /4096)*alpha + att0
__global__ __launch_bounds__(256) void att_s_fin_k(
    const float* __restrict__ P, const float* __restrict__ alphas,
    const float* __restrict__ att0s, float* __restrict__ att)
{
    const int n = blockIdx.x / 3, s = blockIdx.x % 3;
    const float* Pp = P + ((size_t)n * 3 + s) * 8192;
    const float al = alphas[s];
    for (int p = threadIdx.x; p < 625; p += 256) {
        const int u = p / 25, v = p - u * 25;
        float sum = 0.f;
        #pragma unroll
        for (int tc = 0; tc < 8; ++tc) sum += Pp[tc * 1024 + u * 32 + v];
        att[((size_t)n * 3 + s) * 625 + p] = tanhf(sum * (1.0f / 4096.0f)) * al + att0s[s * 625 + p];
    }
}

// ============ temporal scores via MFMA + fused tanh/mask epilogue ============
__global__ __launch_bounds__(256) void att_t_mfma_k(
    const f16* __restrict__ QKT,
    const float* __restrict__ alphat_b, const float* __restrict__ alphat_f,
    float* __restrict__ att)
{
    __shared__ f16 Qs[64 * 72];
    __shared__ f16 Ks[64 * 72];
    const int n = blockIdx.x >> 2, r = blockIdx.x & 3;
    const int br = r >> 1, s = r & 1;
    const int qg = ((br == 0) ? s : 2 + s) * 64;
    const int kg = ((br == 0) ? 4 + s : 6 + s) * 64;
    const f16* Qn = QKT + (size_t)n * 1600 * 512;
    const int tid = threadIdx.x;
    const int w = tid >> 6, lane = tid & 63;
    const int lg = lane >> 4, lr = lane & 15;
    const int srow = tid >> 2, scol = (tid & 3) * 16;
    f32x4 acc[4] = {};

    for (int v = 0; v < 25; ++v) {
        const f16* rowp = Qn + (size_t)(srow * 25 + v) * 512;
        uint4 q0 = *(const uint4*)(rowp + qg + scol);
        uint4 q1 = *(const uint4*)(rowp + qg + scol + 8);
        uint4 k0 = *(const uint4*)(rowp + kg + scol);
        uint4 k1 = *(const uint4*)(rowp + kg + scol + 8);
        __syncthreads();
        *(uint4*)&Qs[srow * 72 + scol] = q0;
        *(uint4*)&Qs[srow * 72 + scol + 8] = q1;
        *(uint4*)&Ks[srow * 72 + scol] = k0;
        *(uint4*)&Ks[srow * 72 + scol + 8] = k1;
        __syncthreads();
        #pragma unroll
        for (int kb = 0; kb < 2; ++kb) {
            f16x8 a = *(const f16x8*)&Qs[(w * 16 + lr) * 72 + kb * 32 + lg * 8];
            #pragma unroll
            for (int ct = 0; ct < 4; ++ct) {
                f16x8 b = *(const f16x8*)&Ks[(ct * 16 + lr) * 72 + kb * 32 + lg * 8];
                acc[ct] = __builtin_amdgcn_mfma_f32_16x16x32_f16(a, b, acc[ct], 0, 0, 0);
            }
        }
    }
    const float al = (br == 0) ? alphat_f[s] : alphat_b[s];
    float* ap = att + (((size_t)n * 2 + br) * 2 + s) * 4096;
    #pragma unroll
    for (int ct = 0; ct < 4; ++ct) {
        #pragma unroll
        for (int rr = 0; rr < 4; ++rr) {
            const int t = w * 16 + lg * 4 + rr;
            const int q = ct * 16 + lr;
            const bool keep = (br == 0) ? (t >= q) : (q >= t);
            ap[t * 64 + q] = keep ? tanhf(acc[ct][rr] * (1.0f / 1600.0f)) * al : 0.0f;
        }
    }
}

// ============ apply spatial att via MFMA ============
__global__ __launch_bounds__(256) void apply_s_mfma_k(
    const f16* __restrict__ xBp, const float* __restrict__ att, f16* __restrict__ y1T)
{
    __shared__ f16 As[3 * 32 * 48];
    const int n = blockIdx.x >> 6, t = blockIdx.x & 63;
    const int tid = threadIdx.x;
    const int w = tid >> 6, lane = tid & 63;
    const int lg = lane >> 4, lr = lane & 15;
    const float* an = att + (size_t)n * 1875;
    for (int i = tid; i < 3 * 32 * 48; i += 256) {
        int s = i / 1536, r2 = i - s * 1536;
        int v = r2 / 48, u = r2 - v * 48;
        As[i] = (v < 25 && u < 25) ? (f16)an[s * 625 + u * 25 + v] : (f16)0.f;
    }
    __syncthreads();
    const f16* Bn = xBp + (size_t)n * 262144 + (size_t)t * 32;
    f16x8 bf[2];
    #pragma unroll
    for (int ct = 0; ct < 2; ++ct)
        bf[ct] = *(const f16x8*)(Bn + (size_t)(w * 32 + ct * 16 + lr) * 2048 + lg * 8);
    #pragma unroll
    for (int s = 0; s < 3; ++s) {
        f32x4 acc[2][2] = {};
        #pragma unroll
        for (int vt = 0; vt < 2; ++vt) {
            f16x8 a = *(const f16x8*)&As[s * 1536 + (vt * 16 + lr) * 48 + lg * 8];
            #pragma unroll
            for (int ct = 0; ct < 2; ++ct)
                acc[vt][ct] = __builtin_amdgcn_mfma_f32_16x16x32_f16(a, bf[ct], acc[vt][ct], 0, 0, 0);
        }
        #pragma unroll
        for (int vt = 0; vt < 2; ++vt)
            #pragma unroll
            for (int ct = 0; ct < 2; ++ct)
                #pragma unroll
                for (int rr = 0; rr < 4; ++rr) {
                    const int v = vt * 16 + lg * 4 + rr;
                    if (v < 25) {
                        const int c = w * 32 + ct * 16 + lr;
                        y1T[((size_t)n * 1600 + t * 25 + v) * 384 + s * 128 + c] = (f16)acc[vt][ct][rr];
                    }
                }
    }
}

// ============ y2T (Nc,1600,128) -> Y2B (Nc,25,128,64) [v][c][t] ============
__global__ __launch_bounds__(256) void t_to_B_k(
    const f16* __restrict__ y2T, f16* __restrict__ Y2B)
{
    __shared__ f16 L[64 * 136];
    const int n = blockIdx.x, v = blockIdx.y;
    const f16* Yn = y2T + (size_t)n * 204800;
    const int tid = threadIdx.x;
    for (int i = tid; i < 1024; i += 256) {
        int t = i >> 4, c8 = (i & 15) * 8;
        *(f16x8*)&L[t * 136 + c8] = *(const f16x8*)&Yn[(size_t)(t * 25 + v) * 128 + c8];
    }
    __syncthreads();
    const int c = tid >> 1, t0 = (tid & 1) * 32;
    f16* dst = Y2B + ((size_t)n * 25 + v) * 8192 + (size_t)c * 64 + t0;
    #pragma unroll
    for (int j = 0; j < 4; ++j) {
        f16x8 o;
        #pragma unroll
        for (int e = 0; e < 8; ++e) o[e] = L[(t0 + j * 8 + e) * 136 + c];
        *(f16x8*)(dst + j * 8) = o;
    }
}

// ============ apply temporal att via MFMA — one block serves all 4 r (wave w = r) ============
__global__ __launch_bounds__(256) void apply_t_mfma_k(
    const f16* __restrict__ Y2B, const float* __restrict__ att, f16* __restrict__ zT)
{
    __shared__ f16 AsT[4][64 * 72];
    const int n = blockIdx.x;
    const int by = blockIdx.y;
    const int vg = by >> 1;
    const int ch = (by & 1) * 64;
    const int tid = threadIdx.x;
    const int w = tid >> 6, lane = tid & 63;
    const int lg = lane >> 4, lr = lane & 15;
    const float* ap = att + (size_t)n * 4 * 4096;
    for (int i = tid; i < 4 * 4096; i += 256) {
        int r = i >> 12, rem = i & 4095;
        int t = rem >> 6, q = rem & 63;
        AsT[r][q * 72 + t] = (f16)ap[i];
    }
    __syncthreads();
    f16x8 af[4][2];
    #pragma unroll
    for (int qt = 0; qt < 4; ++qt)
        #pragma unroll
        for (int kb = 0; kb < 2; ++kb)
            af[qt][kb] = *(const f16x8*)&AsT[w][(qt * 16 + lr) * 72 + kb * 32 + lg * 8];

    for (int vi = 0; vi < 5; ++vi) {
        const int v = vg * 5 + vi;
        const f16* Bv = Y2B + ((size_t)n * 25 + v) * 8192 + (size_t)ch * 64;
        f32x4 acc[4][4] = {};
        #pragma unroll
        for (int kb = 0; kb < 2; ++kb)
            #pragma unroll
            for (int ct = 0; ct < 4; ++ct) {
                f16x8 bf = *(const f16x8*)(Bv + (size_t)(ct * 16 + lr) * 64 + kb * 32 + lg * 8);
                #pragma unroll
                for (int qt = 0; qt < 4; ++qt)
                    acc[qt][ct] = __builtin_amdgcn_mfma_f32_16x16x32_f16(af[qt][kb], bf, acc[qt][ct], 0, 0, 0);
            }
        #pragma unroll
        for (int qt = 0; qt < 4; ++qt)
            #pragma unroll
            for (int ct = 0; ct < 4; ++ct)
                #pragma unroll
                for (int rr = 0; rr < 4; ++rr) {
                    const int q = qt * 16 + lg * 4 + rr;
                    const int c = ch + ct * 16 + lr;
                    zT[((size_t)n * 1600 + q * 25 + v) * 512 + w * 128 + c] = (f16)acc[qt][ct][rr];
                }
    }
}

extern "C" void kernel_launch(void* const* d_in, const int* in_sizes, int n_in,
                              void* d_out, int out_size, void* d_ws, size_t ws_size,
                              hipStream_t stream) {
    const float* x       = (const float*)d_in[0];
    const float* W_ins   = (const float*)d_in[1];
    const float* b_ins   = (const float*)d_in[2];
    const float* alphas  = (const float*)d_in[3];
    const float* att0s   = (const float*)d_in[4];
    const float* W_outs  = (const float*)d_in[5];
    const float* b_outs  = (const float*)d_in[6];
    const float* g_outs  = (const float*)d_in[7];
    const float* be_outs = (const float*)d_in[8];
    const float* W_ffs   = (const float*)d_in[9];
    const float* b_ffs   = (const float*)d_in[10];
    const float* g_ffs   = (const float*)d_in[11];
    const float* be_ffs  = (const float*)d_in[12];
    const float* W_int   = (const float*)d_in[13];
    const float* b_int   = (const float*)d_in[14];
    const float* alphat_b= (const float*)d_in[15];
    const float* alphat_f= (const float*)d_in[16];
    const float* W_outt  = (const float*)d_in[17];
    const float* b_outt  = (const float*)d_in[18];
    const float* g_outt  = (const float*)d_in[19];
    const float* be_outt = (const float*)d_in[20];
    const float* W_fft   = (const float*)d_in[21];
    const float* b_fft   = (const float*)d_in[22];
    const float* g_fft   = (const float*)d_in[23];
    const float* be_fft  = (const float*)d_in[24];
    const float* W_tcn   = (const float*)d_in[25];
    const float* b_tcn   = (const float*)d_in[26];
    const float* g_tcn   = (const float*)d_in[27];
    const float* be_tcn  = (const float*)d_in[28];

    // ---- weights (f16) at workspace head ----
    f16* wf = (f16*)d_ws;
    f16* W_ins16  = wf;            // 49152
    f16* W_outs16 = wf + 49152;    // 49152
    f16* W_ffs16  = wf + 98304;    // 16384
    f16* W_int16  = wf + 114688;   // 65536
    f16* W_outt16 = wf + 180224;   // 65536
    f16* W_fft16  = wf + 245760;   // 16384
    f16* W_tcn16  = wf + 262144;   // 114688  -> end 376832 f16 = 753664 B
    const size_t wbytes = 753664;

    // per-n f16: A 819200, B/C/D 204800, Y2B 204800, xBp 262144
    // aliases: P,attS -> Y2B (dead until 5b); attT -> B (B otherwise unused now)
    const size_t perN = (819200ull + 3ull * 204800ull + 204800ull + 262144ull) * 2ull;
    int Nc = 64;
    while (Nc > 4 && wbytes + (size_t)Nc * perN > ws_size) Nc >>= 1;

    f16* A   = (f16*)((char*)d_ws + wbytes);
    f16* B   = A   + (size_t)Nc * 819200;
    f16* C   = B   + (size_t)Nc * 204800;
    f16* D   = C   + (size_t)Nc * 204800;   // xT, later z2
    f16* Y2B = D   + (size_t)Nc * 204800;
    f16* xBp = Y2B + (size_t)Nc * 204800;
    float* P    = (float*)Y2B;
    float* attS = (float*)Y2B + (size_t)Nc * 24576;
    float* attT = (float*)B;
    // NOTE: attT must NOT alias xBp (round-8 NaN-on-replay bug).

    prep_w_k<<<1472, 256, 0, stream>>>(W_ins, W_outs, W_ffs, W_int, W_outt, W_fft, W_tcn, wf);

    for (int n0 = 0; n0 < 64; n0 += Nc) {
        const float* xc = x + (size_t)n0 * 204800;
        float* outc     = (float*)d_out + (size_t)n0 * 204800;

        // 0) xT + padded x for apply_s
        x_to_T_k<<<dim3(25, 2, Nc), 256, 0, stream>>>(xc, D, xBp);
        // 1) qk_s = W_ins @ x + b_ins          -> A (1600,384)
        gemm_t_k<0><<<dim3(25, 6, Nc), 256, 0, stream>>>(D, W_ins16, b_ins, nullptr, nullptr,
                                                         nullptr, A, 128, 384);
        // 2) spatial scores: partials + finalize
        att_s_mfma_k<<<dim3(24 * Nc), 256, 0, stream>>>(A, P);
        att_s_fin_k<<<dim3(3 * Nc), 256, 0, stream>>>(P, alphas, att0s, attS);
        // 3) y1 = x ⊗ att_s (MFMA)             -> A (1600,384)
        apply_s_mfma_k<<<dim3(64 * Nc), 256, 0, stream>>>(xBp, attS, A);
        // 4+5) y2 = epi(W_ffs @ epi(W_outs @ y1)) fused, y LDS-only -> C
        fused2_k<384><<<dim3(25, 1, Nc), 256, 0, stream>>>(A, W_outs16, b_outs, g_outs, be_outs,
                                                           W_ffs16, b_ffs, g_ffs, be_ffs, D, C);
        // 5b) Y2B = y2 transposed to [v][c][t]  (clobbers P/attS — dead)
        t_to_B_k<<<dim3(Nc, 25), 256, 0, stream>>>(C, Y2B);
        // 6) qk_t = W_int @ y2 + b_int         -> A (1600,512)
        gemm_t_k<0><<<dim3(25, 8, Nc), 256, 0, stream>>>(C, W_int16, b_int, nullptr, nullptr,
                                                         nullptr, A, 128, 512);
        // 7) temporal scores -> attT (aliases B)
        att_t_mfma_k<<<dim3(4 * Nc), 256, 0, stream>>>(A, alphat_b, alphat_f, attT);
        // 8) z_cat = y2 ⊗ att_t (MFMA)         -> A (1600,512)
        apply_t_mfma_k<<<dim3(Nc, 10), 256, 0, stream>>>(Y2B, attT, A);
        // 9+10) z2 = epi(W_fft @ epi(W_outt @ z_cat)) fused, z LDS-only -> D (xT dead)
        fused2_k<512><<<dim3(25, 1, Nc), 256, 0, stream>>>(A, W_outt16, b_outt, g_outt, be_outt,
                                                           W_fft16, b_fft, g_fft, be_fft, C, D);
        // 11) outT = lrelu(z2 + bn(tcn(z2)))   -> A (1600,128)
        tcn_T_k<<<dim3(25, 2, Nc), 256, 0, stream>>>(D, W_tcn16, b_tcn, g_tcn, be_tcn, A);
        // 12) transpose back to fp32 NCHW
        T_to_out_k<<<dim3(25, 1, Nc), 256, 0, stream>>>(A, outc);
    }
}

// Round 13
// 425.776 us; speedup vs baseline: 1.0127x; 1.0127x over previous
//
#include <hip/hip_runtime.h>

#define BNSC 0.99999500003749963f

typedef _Float16 f16;
typedef _Float16 f16x8 __attribute__((ext_vector_type(8)));
typedef float    f32x4 __attribute__((ext_vector_type(4)));

static __device__ __forceinline__ float lrelu_f(float a) { return a >= 0.0f ? a : 0.1f * a; }

// XCD-locality swizzle (bijective; identity when (GX*GZ)%8 != 0).
static __device__ __forceinline__ void xcd_swz(int& bx, int& by, int& bz) {
    const int GX = gridDim.x, GY = gridDim.y, GZ = gridDim.z;
    if (((GX * GZ) & 7) == 0) {
        const int lin = blockIdx.x + GX * (blockIdx.y + GY * blockIdx.z);
        const int xcd = lin & 7;
        const int rest = lin >> 3;
        by = rest % GY;
        const int g = (rest / GY) * 8 + xcd;
        bx = g % GX;
        bz = g / GX;
    } else {
        bx = blockIdx.x; by = blockIdx.y; bz = blockIdx.z;
    }
}

// ============ weight prep: fp32 -> f16 copies (+ tcn permute (m,k,tau)->(tau,m,k)) ============
__global__ __launch_bounds__(256) void prep_w_k(
    const float* __restrict__ Wins, const float* __restrict__ Wouts,
    const float* __restrict__ Wffs, const float* __restrict__ Wint,
    const float* __restrict__ Woutt, const float* __restrict__ Wfft,
    const float* __restrict__ Wtcn, f16* __restrict__ dst)
{
    int i = blockIdx.x * 256 + threadIdx.x;
    int o = 0;
    if (i < 49152) { dst[o + i] = (f16)Wins[i];  return; } i -= 49152; o += 49152;
    if (i < 49152) { dst[o + i] = (f16)Wouts[i]; return; } i -= 49152; o += 49152;
    if (i < 16384) { dst[o + i] = (f16)Wffs[i];  return; } i -= 16384; o += 16384;
    if (i < 65536) { dst[o + i] = (f16)Wint[i];  return; } i -= 65536; o += 65536;
    if (i < 65536) { dst[o + i] = (f16)Woutt[i]; return; } i -= 65536; o += 65536;
    if (i < 16384) { dst[o + i] = (f16)Wfft[i];  return; } i -= 16384; o += 16384;
    if (i < 114688) {
        int tau = i / 16384, rem = i - tau * 16384;      // rem = m*128 + k
        dst[o + i] = (f16)Wtcn[(size_t)rem * 7 + tau];
    }
}

// ============ x (n,128,1600) fp32 -> xT (n,1600,128) f16  AND xBp (n,128,64,32) f16 ============
__global__ __launch_bounds__(256) void x_to_T_k(const float* __restrict__ x,
                                                f16* __restrict__ xT, f16* __restrict__ xBp)
{
    __shared__ float L[64 * 68];
    const int n = blockIdx.z, tv0 = blockIdx.x * 64, c0 = blockIdx.y * 64;
    const int tid = threadIdx.x;
    const int cc = tid >> 4, tv4 = (tid & 15) * 4;
    f16* xBn = xBp + (size_t)n * 262144;
    #pragma unroll
    for (int p = 0; p < 4; ++p) {
        const int c = cc + p * 16;
        float4 v = *(const float4*)&x[((size_t)n * 128 + c0 + c) * 1600 + tv0 + tv4];
        *(float4*)&L[c * 68 + tv4] = v;
        const float vv[4] = {v.x, v.y, v.z, v.w};
        #pragma unroll
        for (int e = 0; e < 4; ++e) {
            const int tvg = tv0 + tv4 + e;
            const int t = tvg / 25, u = tvg - t * 25;
            xBn[(size_t)(c0 + c) * 2048 + t * 32 + u] = (f16)vv[e];
        }
    }
    __syncthreads();
    const int tv = tid & 63, cb = (tid >> 6) * 16;
    f16x8 o0, o1;
    #pragma unroll
    for (int i = 0; i < 8; ++i) o0[i] = (f16)L[(cb + i) * 68 + tv];
    #pragma unroll
    for (int i = 0; i < 8; ++i) o1[i] = (f16)L[(cb + 8 + i) * 68 + tv];
    f16* dst = &xT[((size_t)n * 1600 + tv0 + tv) * 128 + c0 + cb];
    *(f16x8*)dst = o0;
    *(f16x8*)(dst + 8) = o1;
}

// ============ outT (n,1600,128) f16 -> out (n,128,1600) fp32 ============
__global__ __launch_bounds__(256) void T_to_out_k(const f16* __restrict__ oT, float* __restrict__ out)
{
    __shared__ float L[128 * 69];
    const int n = blockIdx.z, tv0 = blockIdx.x * 64;
    const int tid = threadIdx.x;
    #pragma unroll
    for (int p = 0; p < 4; ++p) {
        int idx = tid + p * 256;
        int tv = idx >> 4, c8 = (idx & 15) * 8;
        f16x8 v = *(const f16x8*)&oT[((size_t)n * 1600 + tv0 + tv) * 128 + c8];
        #pragma unroll
        for (int i = 0; i < 8; ++i) L[(c8 + i) * 69 + tv] = (float)v[i];
    }
    __syncthreads();
    const int c = tid >> 1, tvb = (tid & 1) * 32;
    #pragma unroll
    for (int j = 0; j < 8; ++j) {
        float4 o;
        o.x = L[c * 69 + tvb + j * 4 + 0];
        o.y = L[c * 69 + tvb + j * 4 + 1];
        o.z = L[c * 69 + tvb + j * 4 + 2];
        o.w = L[c * 69 + tvb + j * 4 + 3];
        *(float4*)&out[((size_t)n * 128 + c) * 1600 + tv0 + tvb + j * 4] = o;
    }
}

// ============ T-layout MFMA GEMM (64x64 tile, BK=128), conflict-free staging ========
// Staging uses the round-5 measured-zero pattern: each lane one b128 per (row, col-half).
template<int EPI>
__global__ __launch_bounds__(256) void gemm_t_k(
    const f16* __restrict__ A, const f16* __restrict__ W,
    const float* __restrict__ bias,
    const float* __restrict__ g, const float* __restrict__ be,
    const f16* __restrict__ res, f16* __restrict__ out,
    int K, int M)
{
    __shared__ __align__(16) char smem[34816];
    f16* As = (f16*)smem;
    f16* Bs = (f16*)(smem + 17408);
    float* Ss = (float*)smem;
    int bx, by, bz;
    xcd_swz(bx, by, bz);
    const int n = bz, tv0 = bx * 64, m0 = by * 64;
    const int tid = threadIdx.x;
    const int w = tid >> 6, lane = tid & 63;
    const int wr = w >> 1, wc = w & 1;
    const int lg = lane >> 4, lr = lane & 15;
    const int srow = tid >> 3;        // 0..31
    const int sc8 = (tid & 7) * 8;    // 16B chunk within each 64-col half
    const f16* An = A + (size_t)n * 1600 * K;
    f32x4 acc[2][2] = {};

    for (int k0 = 0; k0 < K; k0 += 128) {
        const f16* ar0 = An + (size_t)(tv0 + srow) * K + k0;
        const f16* ar1 = An + (size_t)(tv0 + srow + 32) * K + k0;
        const f16* br0 = W + (size_t)(m0 + srow) * K + k0;
        const f16* br1 = W + (size_t)(m0 + srow + 32) * K + k0;
        uint4 a00 = *(const uint4*)(ar0 + sc8),      a01 = *(const uint4*)(ar0 + 64 + sc8);
        uint4 a10 = *(const uint4*)(ar1 + sc8),      a11 = *(const uint4*)(ar1 + 64 + sc8);
        uint4 b00 = *(const uint4*)(br0 + sc8),      b01 = *(const uint4*)(br0 + 64 + sc8);
        uint4 b10 = *(const uint4*)(br1 + sc8),      b11 = *(const uint4*)(br1 + 64 + sc8);
        __syncthreads();
        *(uint4*)&As[srow * 136 + sc8]             = a00;
        *(uint4*)&As[srow * 136 + 64 + sc8]        = a01;
        *(uint4*)&As[(srow + 32) * 136 + sc8]      = a10;
        *(uint4*)&As[(srow + 32) * 136 + 64 + sc8] = a11;
        *(uint4*)&Bs[srow * 136 + sc8]             = b00;
        *(uint4*)&Bs[srow * 136 + 64 + sc8]        = b01;
        *(uint4*)&Bs[(srow + 32) * 136 + sc8]      = b10;
        *(uint4*)&Bs[(srow + 32) * 136 + 64 + sc8] = b11;
        __syncthreads();
        #pragma unroll
        for (int kb = 0; kb < 128; kb += 32) {
            f16x8 af0 = *(const f16x8*)&As[(wr * 32 + lr) * 136 + kb + lg * 8];
            f16x8 af1 = *(const f16x8*)&As[(wr * 32 + 16 + lr) * 136 + kb + lg * 8];
            f16x8 bf0 = *(const f16x8*)&Bs[(wc * 32 + lr) * 136 + kb + lg * 8];
            f16x8 bf1 = *(const f16x8*)&Bs[(wc * 32 + 16 + lr) * 136 + kb + lg * 8];
            acc[0][0] = __builtin_amdgcn_mfma_f32_16x16x32_f16(af0, bf0, acc[0][0], 0, 0, 0);
            acc[0][1] = __builtin_amdgcn_mfma_f32_16x16x32_f16(af0, bf1, acc[0][1], 0, 0, 0);
            acc[1][0] = __builtin_amdgcn_mfma_f32_16x16x32_f16(af1, bf0, acc[1][0], 0, 0, 0);
            acc[1][1] = __builtin_amdgcn_mfma_f32_16x16x32_f16(af1, bf1, acc[1][1], 0, 0, 0);
        }
        __syncthreads();
    }
    #pragma unroll
    for (int fi = 0; fi < 2; ++fi)
        #pragma unroll
        for (int fj = 0; fj < 2; ++fj)
            #pragma unroll
            for (int rr = 0; rr < 4; ++rr)
                Ss[(wr * 32 + fi * 16 + lg * 4 + rr) * 68 + wc * 32 + fj * 16 + lr] = acc[fi][fj][rr];
    __syncthreads();
    const int tvl = tid >> 2, mq = (tid & 3) * 16;
    const int tv = tv0 + tvl;
    const int m  = m0 + mq;
    float vals[16];
    #pragma unroll
    for (int j = 0; j < 4; ++j)
        *(float4*)&vals[j * 4] = *(const float4*)&Ss[tvl * 68 + mq + j * 4];
    float bi[16];
    #pragma unroll
    for (int j = 0; j < 4; ++j) *(float4*)&bi[j * 4] = *(const float4*)&bias[m + j * 4];
    if (EPI == 1) {
        float gg[16], bb[16];
        #pragma unroll
        for (int j = 0; j < 4; ++j) {
            *(float4*)&gg[j * 4] = *(const float4*)&g[m + j * 4];
            *(float4*)&bb[j * 4] = *(const float4*)&be[m + j * 4];
        }
        const f16* rp = res + ((size_t)n * 1600 + tv) * M + m;
        f16x8 r0 = *(const f16x8*)rp;
        f16x8 r1 = *(const f16x8*)(rp + 8);
        #pragma unroll
        for (int j = 0; j < 16; ++j) {
            float r = (float)((j < 8) ? r0[j & 7] : r1[j & 7]);
            vals[j] = lrelu_f(r + (vals[j] + bi[j]) * (gg[j] * BNSC) + bb[j]);
        }
    } else {
        #pragma unroll
        for (int j = 0; j < 16; ++j) vals[j] += bi[j];
    }
    f16x8 o0, o1;
    #pragma unroll
    for (int j = 0; j < 8; ++j) { o0[j] = (f16)vals[j]; o1[j] = (f16)vals[8 + j]; }
    f16* op = out + ((size_t)n * 1600 + tv) * M + m;
    *(f16x8*)op = o0;
    *(f16x8*)(op + 8) = o1;
}

// ============ FUSED dual GEMM: out = epi2(W2 @ epi1(W1 @ Ain)), M1=M2=K2=128 ============
template<int K1>
__global__ __launch_bounds__(256) void fused2_k(
    const f16* __restrict__ Ain,
    const f16* __restrict__ W1,
    const float* __restrict__ b1, const float* __restrict__ g1, const float* __restrict__ be1,
    const f16* __restrict__ W2,
    const float* __restrict__ b2, const float* __restrict__ g2, const float* __restrict__ be2,
    const f16* __restrict__ res,
    f16* __restrict__ out)
{
    __shared__ __align__(16) char smem[35840];
    f16* As1  = (f16*)smem;                 // 64 x 72
    f16* Bs1  = (f16*)(smem + 9216);        // 128 x 72
    float* Ss = (float*)smem;               // 64 x 132 f32
    f16* Ys   = (f16*)smem;                 // 64 x 136
    f16* Bs2  = (f16*)(smem + 17408);       // 128 x 72
    int bx, by, bz;
    xcd_swz(bx, by, bz);
    const int n = bz, tv0 = bx * 64;
    const int tid = threadIdx.x;
    const int w = tid >> 6, lane = tid & 63;
    const int wr = w >> 1, wc = w & 1;
    const int lg = lane >> 4, lr = lane & 15;
    const int srow = tid >> 3, sc = (tid & 7) * 8;
    const f16* An = Ain + (size_t)n * 1600 * K1;
    const f16* rn = res + ((size_t)n * 1600 + tv0) * 128;

    f32x4 acc[2][4] = {};
    for (int k0 = 0; k0 < K1; k0 += 64) {
        uint4 a0 = *(const uint4*)(An + (size_t)(tv0 + srow) * K1 + k0 + sc);
        uint4 a1 = *(const uint4*)(An + (size_t)(tv0 + srow + 32) * K1 + k0 + sc);
        uint4 w0 = *(const uint4*)(W1 + (size_t)srow * K1 + k0 + sc);
        uint4 w1v = *(const uint4*)(W1 + (size_t)(srow + 32) * K1 + k0 + sc);
        uint4 w2v = *(const uint4*)(W1 + (size_t)(srow + 64) * K1 + k0 + sc);
        uint4 w3v = *(const uint4*)(W1 + (size_t)(srow + 96) * K1 + k0 + sc);
        __syncthreads();
        *(uint4*)&As1[srow * 72 + sc] = a0;
        *(uint4*)&As1[(srow + 32) * 72 + sc] = a1;
        *(uint4*)&Bs1[srow * 72 + sc] = w0;
        *(uint4*)&Bs1[(srow + 32) * 72 + sc] = w1v;
        *(uint4*)&Bs1[(srow + 64) * 72 + sc] = w2v;
        *(uint4*)&Bs1[(srow + 96) * 72 + sc] = w3v;
        __syncthreads();
        #pragma unroll
        for (int kb = 0; kb < 64; kb += 32) {
            f16x8 af0 = *(const f16x8*)&As1[(wr * 32 + lr) * 72 + kb + lg * 8];
            f16x8 af1 = *(const f16x8*)&As1[(wr * 32 + 16 + lr) * 72 + kb + lg * 8];
            #pragma unroll
            for (int ft = 0; ft < 4; ++ft) {
                f16x8 bf = *(const f16x8*)&Bs1[(wc * 64 + ft * 16 + lr) * 72 + kb + lg * 8];
                acc[0][ft] = __builtin_amdgcn_mfma_f32_16x16x32_f16(af0, bf, acc[0][ft], 0, 0, 0);
                acc[1][ft] = __builtin_amdgcn_mfma_f32_16x16x32_f16(af1, bf, acc[1][ft], 0, 0, 0);
            }
        }
        __syncthreads();
    }
    #pragma unroll
    for (int fi = 0; fi < 2; ++fi)
        #pragma unroll
        for (int ft = 0; ft < 4; ++ft)
            #pragma unroll
            for (int rr = 0; rr < 4; ++rr)
                Ss[(wr * 32 + fi * 16 + lg * 4 + rr) * 132 + wc * 64 + ft * 16 + lr] = acc[fi][ft][rr];
    __syncthreads();
    const int tvl = tid >> 2, q4 = (tid & 3) * 16;
    f16x8 yh[4];
    #pragma unroll
    for (int mh = 0; mh < 2; ++mh) {
        const int mq = mh * 64 + q4;
        float vals[16], bb[16], gg[16], eb[16];
        #pragma unroll
        for (int j = 0; j < 4; ++j) {
            *(float4*)&vals[j * 4] = *(const float4*)&Ss[tvl * 132 + mq + j * 4];
            *(float4*)&bb[j * 4]   = *(const float4*)&b1[mq + j * 4];
            *(float4*)&gg[j * 4]   = *(const float4*)&g1[mq + j * 4];
            *(float4*)&eb[j * 4]   = *(const float4*)&be1[mq + j * 4];
        }
        const f16* rp = rn + (size_t)tvl * 128 + mq;
        f16x8 r0 = *(const f16x8*)rp, r1 = *(const f16x8*)(rp + 8);
        #pragma unroll
        for (int j = 0; j < 16; ++j) {
            float r = (float)((j < 8) ? r0[j & 7] : r1[j & 7]);
            vals[j] = lrelu_f(r + (vals[j] + bb[j]) * (gg[j] * BNSC) + eb[j]);
        }
        #pragma unroll
        for (int j = 0; j < 8; ++j) {
            yh[mh * 2][j]     = (f16)vals[j];
            yh[mh * 2 + 1][j] = (f16)vals[8 + j];
        }
    }
    __syncthreads();
    *(f16x8*)&Ys[tvl * 136 + q4]          = yh[0];
    *(f16x8*)&Ys[tvl * 136 + q4 + 8]      = yh[1];
    *(f16x8*)&Ys[tvl * 136 + 64 + q4]     = yh[2];
    *(f16x8*)&Ys[tvl * 136 + 64 + q4 + 8] = yh[3];

    f32x4 acc2[2][4] = {};
    for (int k2 = 0; k2 < 128; k2 += 64) {
        uint4 w0 = *(const uint4*)(W2 + (size_t)srow * 128 + k2 + sc);
        uint4 w1v = *(const uint4*)(W2 + (size_t)(srow + 32) * 128 + k2 + sc);
        uint4 w2v = *(const uint4*)(W2 + (size_t)(srow + 64) * 128 + k2 + sc);
        uint4 w3v = *(const uint4*)(W2 + (size_t)(srow + 96) * 128 + k2 + sc);
        __syncthreads();
        *(uint4*)&Bs2[srow * 72 + sc] = w0;
        *(uint4*)&Bs2[(srow + 32) * 72 + sc] = w1v;
        *(uint4*)&Bs2[(srow + 64) * 72 + sc] = w2v;
        *(uint4*)&Bs2[(srow + 96) * 72 + sc] = w3v;
        __syncthreads();
        #pragma unroll
        for (int kb = 0; kb < 64; kb += 32) {
            f16x8 af0 = *(const f16x8*)&Ys[(wr * 32 + lr) * 136 + k2 + kb + lg * 8];
            f16x8 af1 = *(const f16x8*)&Ys[(wr * 32 + 16 + lr) * 136 + k2 + kb + lg * 8];
            #pragma unroll
            for (int ft = 0; ft < 4; ++ft) {
                f16x8 bf = *(const f16x8*)&Bs2[(wc * 64 + ft * 16 + lr) * 72 + kb + lg * 8];
                acc2[0][ft] = __builtin_amdgcn_mfma_f32_16x16x32_f16(af0, bf, acc2[0][ft], 0, 0, 0);
                acc2[1][ft] = __builtin_amdgcn_mfma_f32_16x16x32_f16(af1, bf, acc2[1][ft], 0, 0, 0);
            }
        }
    }
    __syncthreads();
    #pragma unroll
    for (int fi = 0; fi < 2; ++fi)
        #pragma unroll
        for (int ft = 0; ft < 4; ++ft)
            #pragma unroll
            for (int rr = 0; rr < 4; ++rr)
                Ss[(wr * 32 + fi * 16 + lg * 4 + rr) * 132 + wc * 64 + ft * 16 + lr] = acc2[fi][ft][rr];
    __syncthreads();
    f16* op = out + ((size_t)n * 1600 + tv0 + tvl) * 128;
    #pragma unroll
    for (int mh = 0; mh < 2; ++mh) {
        const int mq = mh * 64 + q4;
        float vals[16], bb[16], gg[16], eb[16];
        #pragma unroll
        for (int j = 0; j < 4; ++j) {
            *(float4*)&vals[j * 4] = *(const float4*)&Ss[tvl * 132 + mq + j * 4];
            *(float4*)&bb[j * 4]   = *(const float4*)&b2[mq + j * 4];
            *(float4*)&gg[j * 4]   = *(const float4*)&g2[mq + j * 4];
            *(float4*)&eb[j * 4]   = *(const float4*)&be2[mq + j * 4];
        }
        const f16* rp = rn + (size_t)tvl * 128 + mq;
        f16x8 r0 = *(const f16x8*)rp, r1 = *(const f16x8*)(rp + 8);
        #pragma unroll
        for (int j = 0; j < 16; ++j) {
            float r = (float)((j < 8) ? r0[j & 7] : r1[j & 7]);
            vals[j] = lrelu_f(r + (vals[j] + bb[j]) * (gg[j] * BNSC) + eb[j]);
        }
        f16x8 o0, o1;
        #pragma unroll
        for (int j = 0; j < 8; ++j) { o0[j] = (f16)vals[j]; o1[j] = (f16)vals[8 + j]; }
        *(f16x8*)(op + mq) = o0;
        *(f16x8*)(op + mq + 8) = o1;
    }
}

// ============ TCN (64x64 tile, BK=128 per tau), conflict-free staging ============
__global__ __launch_bounds__(256) void tcn_T_k(
    const f16* __restrict__ z2T, const f16* __restrict__ W7,
    const float* __restrict__ bias, const float* __restrict__ g,
    const float* __restrict__ be, f16* __restrict__ outT)
{
    __shared__ __align__(16) char smem[34816];
    f16* As = (f16*)smem;
    f16* Bs = (f16*)(smem + 17408);
    float* Ss = (float*)smem;
    int bx, by, bz;
    xcd_swz(bx, by, bz);
    const int n = bz, tv0 = bx * 64, m0 = by * 64;
    const int tid = threadIdx.x;
    const int w = tid >> 6, lane = tid & 63;
    const int wr = w >> 1, wc = w & 1;
    const int lg = lane >> 4, lr = lane & 15;
    const int srow = tid >> 3;
    const int sc8 = (tid & 7) * 8;
    const f16* Zn = z2T + (size_t)n * 204800;
    f32x4 acc[2][2] = {};

    for (int tau = 0; tau < 7; ++tau) {
        const int shift = (tau - 3) * 25;
        const f16* Wt = W7 + tau * 16384;
        const int gr0 = tv0 + srow + shift;
        const int gr1 = gr0 + 32;
        uint4 a00 = make_uint4(0,0,0,0), a01 = a00, a10 = a00, a11 = a00;
        if (gr0 >= 0 && gr0 < 1600) {
            const f16* p = Zn + (size_t)gr0 * 128;
            a00 = *(const uint4*)(p + sc8); a01 = *(const uint4*)(p + 64 + sc8);
        }
        if (gr1 >= 0 && gr1 < 1600) {
            const f16* p = Zn + (size_t)gr1 * 128;
            a10 = *(const uint4*)(p + sc8); a11 = *(const uint4*)(p + 64 + sc8);
        }
        const f16* br0 = Wt + (size_t)(m0 + srow) * 128;
        const f16* br1 = Wt + (size_t)(m0 + srow + 32) * 128;
        uint4 b00 = *(const uint4*)(br0 + sc8), b01 = *(const uint4*)(br0 + 64 + sc8);
        uint4 b10 = *(const uint4*)(br1 + sc8), b11 = *(const uint4*)(br1 + 64 + sc8);
        __syncthreads();
        *(uint4*)&As[srow * 136 + sc8]             = a00;
        *(uint4*)&As[srow * 136 + 64 + sc8]        = a01;
        *(uint4*)&As[(srow + 32) * 136 + sc8]      = a10;
        *(uint4*)&As[(srow + 32) * 136 + 64 + sc8] = a11;
        *(uint4*)&Bs[srow * 136 + sc8]             = b00;
        *(uint4*)&Bs[srow * 136 + 64 + sc8]        = b01;
        *(uint4*)&Bs[(srow + 32) * 136 + sc8]      = b10;
        *(uint4*)&Bs[(srow + 32) * 136 + 64 + sc8] = b11;
        __syncthreads();
        #pragma unroll
        for (int kb = 0; kb < 128; kb += 32) {
            f16x8 af0 = *(const f16x8*)&As[(wr * 32 + lr) * 136 + kb + lg * 8];
            f16x8 af1 = *(const f16x8*)&As[(wr * 32 + 16 + lr) * 136 + kb + lg * 8];
            f16x8 bf0 = *(const f16x8*)&Bs[(wc * 32 + lr) * 136 + kb + lg * 8];
            f16x8 bf1 = *(const f16x8*)&Bs[(wc * 32 + 16 + lr) * 136 + kb + lg * 8];
            acc[0][0] = __builtin_amdgcn_mfma_f32_16x16x32_f16(af0, bf0, acc[0][0], 0, 0, 0);
            acc[0][1] = __builtin_amdgcn_mfma_f32_16x16x32_f16(af0, bf1, acc[0][1], 0, 0, 0);
            acc[1][0] = __builtin_amdgcn_mfma_f32_16x16x32_f16(af1, bf0, acc[1][0], 0, 0, 0);
            acc[1][1] = __builtin_amdgcn_mfma_f32_16x16x32_f16(af1, bf1, acc[1][1], 0, 0, 0);
        }
        __syncthreads();
    }
    #pragma unroll
    for (int fi = 0; fi < 2; ++fi)
        #pragma unroll
        for (int fj = 0; fj < 2; ++fj)
            #pragma unroll
            for (int rr = 0; rr < 4; ++rr)
                Ss[(wr * 32 + fi * 16 + lg * 4 + rr) * 68 + wc * 32 + fj * 16 + lr] = acc[fi][fj][rr];
    __syncthreads();
    const int tvl = tid >> 2, mq = (tid & 3) * 16;
    const int tv = tv0 + tvl;
    const int m  = m0 + mq;
    float vals[16], bi[16], gg[16], bb[16];
    #pragma unroll
    for (int j = 0; j < 4; ++j) {
        *(float4*)&vals[j * 4] = *(const float4*)&Ss[tvl * 68 + mq + j * 4];
        *(float4*)&bi[j * 4]   = *(const float4*)&bias[m + j * 4];
        *(float4*)&gg[j * 4]   = *(const float4*)&g[m + j * 4];
        *(float4*)&bb[j * 4]   = *(const float4*)&be[m + j * 4];
    }
    const f16* rp = Zn + (size_t)tv * 128 + m;
    f16x8 r0 = *(const f16x8*)rp;
    f16x8 r1 = *(const f16x8*)(rp + 8);
    #pragma unroll
    for (int j = 0; j < 16; ++j) {
        float r = (float)((j < 8) ? r0[j & 7] : r1[j & 7]);
        vals[j] = lrelu_f(r + (vals[j] + bi[j]) * (gg[j] * BNSC) + bb[j]);
    }
    f16x8 o0, o1;
    #pragma unroll
    for (int j = 0; j < 8; ++j) { o0[j] = (f16)vals[j]; o1[j] = (f16)vals[8 + j]; }
    f16* op = outT + ((size_t)n * 1600 + tv) * 128 + m;
    *(f16x8*)op = o0;
    *(f16x8*)(op + 8) = o1;
}

// ============ spatial scores via MFMA, t-chunked partials ============
__global__ __launch_bounds__(256) void att_s_mfma_k(
    const f16* __restrict__ QKT, float* __restrict__ P)
{
    __shared__ float Lred[4][1024];
    const int n = blockIdx.x / 24;
    const int rs = blockIdx.x % 24;
    const int s = rs >> 3, tc = rs & 7;
    const int tid = threadIdx.x;
    const int w = tid >> 6, lane = tid & 63;
    const int lg = lane >> 4, lr = lane & 15;
    const int qc = s * 64, kc = 192 + s * 64;
    const f16* Qn = QKT + (size_t)n * 1600 * 384;
    f32x4 acc[2][2] = {};

    #pragma unroll
    for (int tt = 0; tt < 2; ++tt) {
        const int t = tc * 8 + w * 2 + tt;
        const size_t rbase = (size_t)t * 25;
        #pragma unroll
        for (int kb = 0; kb < 2; ++kb) {
            f16x8 a[2] = {}, b[2] = {};
            #pragma unroll
            for (int rt = 0; rt < 2; ++rt) {
                const int u = rt * 16 + lr;
                if (u < 25) {
                    const f16* rp = Qn + (rbase + u) * 384;
                    a[rt] = *(const f16x8*)(rp + qc + kb * 32 + lg * 8);
                    b[rt] = *(const f16x8*)(rp + kc + kb * 32 + lg * 8);
                }
            }
            #pragma unroll
            for (int rt = 0; rt < 2; ++rt)
                #pragma unroll
                for (int ct = 0; ct < 2; ++ct)
                    acc[rt][ct] = __builtin_amdgcn_mfma_f32_16x16x32_f16(a[rt], b[ct], acc[rt][ct], 0, 0, 0);
        }
    }
    #pragma unroll
    for (int rt = 0; rt < 2; ++rt)
        #pragma unroll
        for (int ct = 0; ct < 2; ++ct)
            #pragma unroll
            for (int rr = 0; rr < 4; ++rr) {
                const int u = rt * 16 + lg * 4 + rr;
                const int v = ct * 16 + lr;
                Lred[w][u * 32 + v] = acc[rt][ct][rr];
            }
    __syncthreads();
    float* Pp = P + (((size_t)n * 3 + s) * 8 + tc) * 1024;
    for (int i = tid; i < 1024; i += 256)
        Pp[i] = Lred[0][i] + Lred[1][i] + Lred[2][i] + Lred[3][i];
}

// finalize: att[n,s,u,v] = tanh(sum_tc P /4096)*alpha + att0
__global__ __launch_bounds__(256) void att_s_fin_k(
    const float* __restrict__ P, const float* __restrict__ alphas,
    const float* __restrict__ att0s, float* __restrict__ att)
{
    const int n = blockIdx.x / 3, s = blockIdx.x % 3;
    const float* Pp = P + ((size_t)n * 3 + s) * 8192;
    const float al = alphas[s];
    for (int p = threadIdx.x; p < 625; p += 256) {
        const int u = p / 25, v = p - u * 25;
        float sum = 0.f;
        #pragma unroll
        for (int tc = 0; tc < 8; ++tc) sum += Pp[tc * 1024 + u * 32 + v];
        att[((size_t)n * 3 + s) * 625 + p] = tanhf(sum * (1.0f / 4096.0f)) * al + att0s[s * 625 + p];
    }
}

// ============ temporal scores via MFMA + fused tanh/mask epilogue ============
__global__ __launch_bounds__(256) void att_t_mfma_k(
    const f16* __restrict__ QKT,
    const float* __restrict__ alphat_b, const float* __restrict__ alphat_f,
    float* __restrict__ att)
{
    __shared__ f16 Qs[64 * 72];
    __shared__ f16 Ks[64 * 72];
    const int n = blockIdx.x >> 2, r = blockIdx.x & 3;
    const int br = r >> 1, s = r & 1;
    const int qg = ((br == 0) ? s : 2 + s) * 64;
    const int kg = ((br == 0) ? 4 + s : 6 + s) * 64;
    const f16* Qn = QKT + (size_t)n * 1600 * 512;
    const int tid = threadIdx.x;
    const int w = tid >> 6, lane = tid & 63;
    const int lg = lane >> 4, lr = lane & 15;
    const int srow = tid >> 2, scol = (tid & 3) * 16;
    f32x4 acc[4] = {};

    for (int v = 0; v < 25; ++v) {
        const f16* rowp = Qn + (size_t)(srow * 25 + v) * 512;
        uint4 q0 = *(const uint4*)(rowp + qg + scol);
        uint4 q1 = *(const uint4*)(rowp + qg + scol + 8);
        uint4 k0 = *(const uint4*)(rowp + kg + scol);
        uint4 k1 = *(const uint4*)(rowp + kg + scol + 8);
        __syncthreads();
        *(uint4*)&Qs[srow * 72 + scol] = q0;
        *(uint4*)&Qs[srow * 72 + scol + 8] = q1;
        *(uint4*)&Ks[srow * 72 + scol] = k0;
        *(uint4*)&Ks[srow * 72 + scol + 8] = k1;
        __syncthreads();
        #pragma unroll
        for (int kb = 0; kb < 2; ++kb) {
            f16x8 a = *(const f16x8*)&Qs[(w * 16 + lr) * 72 + kb * 32 + lg * 8];
            #pragma unroll
            for (int ct = 0; ct < 4; ++ct) {
                f16x8 b = *(const f16x8*)&Ks[(ct * 16 + lr) * 72 + kb * 32 + lg * 8];
                acc[ct] = __builtin_amdgcn_mfma_f32_16x16x32_f16(a, b, acc[ct], 0, 0, 0);
            }
        }
    }
    const float al = (br == 0) ? alphat_f[s] : alphat_b[s];
    float* ap = att + (((size_t)n * 2 + br) * 2 + s) * 4096;
    #pragma unroll
    for (int ct = 0; ct < 4; ++ct) {
        #pragma unroll
        for (int rr = 0; rr < 4; ++rr) {
            const int t = w * 16 + lg * 4 + rr;
            const int q = ct * 16 + lr;
            const bool keep = (br == 0) ? (t >= q) : (q >= t);
            ap[t * 64 + q] = keep ? tanhf(acc[ct][rr] * (1.0f / 1600.0f)) * al : 0.0f;
        }
    }
}

// ============ apply spatial att via MFMA ============
__global__ __launch_bounds__(256) void apply_s_mfma_k(
    const f16* __restrict__ xBp, const float* __restrict__ att, f16* __restrict__ y1T)
{
    __shared__ f16 As[3 * 32 * 48];
    const int n = blockIdx.x >> 6, t = blockIdx.x & 63;
    const int tid = threadIdx.x;
    const int w = tid >> 6, lane = tid & 63;
    const int lg = lane >> 4, lr = lane & 15;
    const float* an = att + (size_t)n * 1875;
    for (int i = tid; i < 3 * 32 * 48; i += 256) {
        int s = i / 1536, r2 = i - s * 1536;
        int v = r2 / 48, u = r2 - v * 48;
        As[i] = (v < 25 && u < 25) ? (f16)an[s * 625 + u * 25 + v] : (f16)0.f;
    }
    __syncthreads();
    const f16* Bn = xBp + (size_t)n * 262144 + (size_t)t * 32;
    f16x8 bf[2];
    #pragma unroll
    for (int ct = 0; ct < 2; ++ct)
        bf[ct] = *(const f16x8*)(Bn + (size_t)(w * 32 + ct * 16 + lr) * 2048 + lg * 8);
    #pragma unroll
    for (int s = 0; s < 3; ++s) {
        f32x4 acc[2][2] = {};
        #pragma unroll
        for (int vt = 0; vt < 2; ++vt) {
            f16x8 a = *(const f16x8*)&As[s * 1536 + (vt * 16 + lr) * 48 + lg * 8];
            #pragma unroll
            for (int ct = 0; ct < 2; ++ct)
                acc[vt][ct] = __builtin_amdgcn_mfma_f32_16x16x32_f16(a, bf[ct], acc[vt][ct], 0, 0, 0);
        }
        #pragma unroll
        for (int vt = 0; vt < 2; ++vt)
            #pragma unroll
            for (int ct = 0; ct < 2; ++ct)
                #pragma unroll
                for (int rr = 0; rr < 4; ++rr) {
                    const int v = vt * 16 + lg * 4 + rr;
                    if (v < 25) {
                        const int c = w * 32 + ct * 16 + lr;
                        y1T[((size_t)n * 1600 + t * 25 + v) * 384 + s * 128 + c] = (f16)acc[vt][ct][rr];
                    }
                }
    }
}

// ============ y2T (Nc,1600,128) -> Y2B (Nc,25,128,64) [v][c][t] ============
__global__ __launch_bounds__(256) void t_to_B_k(
    const f16* __restrict__ y2T, f16* __restrict__ Y2B)
{
    __shared__ f16 L[64 * 136];
    const int n = blockIdx.x, v = blockIdx.y;
    const f16* Yn = y2T + (size_t)n * 204800;
    const int tid = threadIdx.x;
    for (int i = tid; i < 1024; i += 256) {
        int t = i >> 4, c8 = (i & 15) * 8;
        *(f16x8*)&L[t * 136 + c8] = *(const f16x8*)&Yn[(size_t)(t * 25 + v) * 128 + c8];
    }
    __syncthreads();
    const int c = tid >> 1, t0 = (tid & 1) * 32;
    f16* dst = Y2B + ((size_t)n * 25 + v) * 8192 + (size_t)c * 64 + t0;
    #pragma unroll
    for (int j = 0; j < 4; ++j) {
        f16x8 o;
        #pragma unroll
        for (int e = 0; e < 8; ++e) o[e] = L[(t0 + j * 8 + e) * 136 + c];
        *(f16x8*)(dst + j * 8) = o;
    }
}

// ============ apply temporal att via MFMA — one block serves all 4 r (wave w = r) ============
__global__ __launch_bounds__(256) void apply_t_mfma_k(
    const f16* __restrict__ Y2B, const float* __restrict__ att, f16* __restrict__ zT)
{
    __shared__ f16 AsT[4][64 * 72];
    const int n = blockIdx.x;
    const int by = blockIdx.y;
    const int vg = by >> 1;
    const int ch = (by & 1) * 64;
    const int tid = threadIdx.x;
    const int w = tid >> 6, lane = tid & 63;
    const int lg = lane >> 4, lr = lane & 15;
    const float* ap = att + (size_t)n * 4 * 4096;
    for (int i = tid; i < 4 * 4096; i += 256) {
        int r = i >> 12, rem = i & 4095;
        int t = rem >> 6, q = rem & 63;
        AsT[r][q * 72 + t] = (f16)ap[i];
    }
    __syncthreads();
    f16x8 af[4][2];
    #pragma unroll
    for (int qt = 0; qt < 4; ++qt)
        #pragma unroll
        for (int kb = 0; kb < 2; ++kb)
            af[qt][kb] = *(const f16x8*)&AsT[w][(qt * 16 + lr) * 72 + kb * 32 + lg * 8];

    for (int vi = 0; vi < 5; ++vi) {
        const int v = vg * 5 + vi;
        const f16* Bv = Y2B + ((size_t)n * 25 + v) * 8192 + (size_t)ch * 64;
        f32x4 acc[4][4] = {};
        #pragma unroll
        for (int kb = 0; kb < 2; ++kb)
            #pragma unroll
            for (int ct = 0; ct < 4; ++ct) {
                f16x8 bf = *(const f16x8*)(Bv + (size_t)(ct * 16 + lr) * 64 + kb * 32 + lg * 8);
                #pragma unroll
                for (int qt = 0; qt < 4; ++qt)
                    acc[qt][ct] = __builtin_amdgcn_mfma_f32_16x16x32_f16(af[qt][kb], bf, acc[qt][ct], 0, 0, 0);
            }
        #pragma unroll
        for (int qt = 0; qt < 4; ++qt)
            #pragma unroll
            for (int ct = 0; ct < 4; ++ct)
                #pragma unroll
                for (int rr = 0; rr < 4; ++rr) {
                    const int q = qt * 16 + lg * 4 + rr;
                    const int c = ch + ct * 16 + lr;
                    zT[((size_t)n * 1600 + q * 25 + v) * 512 + w * 128 + c] = (f16)acc[qt][ct][rr];
                }
    }
}

extern "C" void kernel_launch(void* const* d_in, const int* in_sizes, int n_in,
                              void* d_out, int out_size, void* d_ws, size_t ws_size,
                              hipStream_t stream) {
    const float* x       = (const float*)d_in[0];
    const float* W_ins   = (const float*)d_in[1];
    const float* b_ins   = (const float*)d_in[2];
    const float* alphas  = (const float*)d_in[3];
    const float* att0s   = (const float*)d_in[4];
    const float* W_outs  = (const float*)d_in[5];
    const float* b_outs  = (const float*)d_in[6];
    const float* g_outs  = (const float*)d_in[7];
    const float* be_outs = (const float*)d_in[8];
    const float* W_ffs   = (const float*)d_in[9];
    const float* b_ffs   = (const float*)d_in[10];
    const float* g_ffs   = (const float*)d_in[11];
    const float* be_ffs  = (const float*)d_in[12];
    const float* W_int   = (const float*)d_in[13];
    const float* b_int   = (const float*)d_in[14];
    const float* alphat_b= (const float*)d_in[15];
    const float* alphat_f= (const float*)d_in[16];
    const float* W_outt  = (const float*)d_in[17];
    const float* b_outt  = (const float*)d_in[18];
    const float* g_outt  = (const float*)d_in[19];
    const float* be_outt = (const float*)d_in[20];
    const float* W_fft   = (const float*)d_in[21];
    const float* b_fft   = (const float*)d_in[22];
    const float* g_fft   = (const float*)d_in[23];
    const float* be_fft  = (const float*)d_in[24];
    const float* W_tcn   = (const float*)d_in[25];
    const float* b_tcn   = (const float*)d_in[26];
    const float* g_tcn   = (const float*)d_in[27];
    const float* be_tcn  = (const float*)d_in[28];

    // ---- weights (f16) at workspace head ----
    f16* wf = (f16*)d_ws;
    f16* W_ins16  = wf;            // 49152
    f16* W_outs16 = wf + 49152;    // 49152
    f16* W_ffs16  = wf + 98304;    // 16384
    f16* W_int16  = wf + 114688;   // 65536
    f16* W_outt16 = wf + 180224;   // 65536
    f16* W_fft16  = wf + 245760;   // 16384
    f16* W_tcn16  = wf + 262144;   // 114688  -> end 376832 f16 = 753664 B
    const size_t wbytes = 753664;

    // per-n f16: A 819200, B/C/D 204800, Y2B 204800, xBp 262144
    const size_t perN = (819200ull + 3ull * 204800ull + 204800ull + 262144ull) * 2ull;
    int Nc = 64;
    while (Nc > 4 && wbytes + (size_t)Nc * perN > ws_size) Nc >>= 1;

    f16* A   = (f16*)((char*)d_ws + wbytes);
    f16* B   = A   + (size_t)Nc * 819200;
    f16* C   = B   + (size_t)Nc * 204800;
    f16* D   = C   + (size_t)Nc * 204800;   // xT, later z2
    f16* Y2B = D   + (size_t)Nc * 204800;
    f16* xBp = Y2B + (size_t)Nc * 204800;
    float* P    = (float*)Y2B;
    float* attS = (float*)Y2B + (size_t)Nc * 24576;
    float* attT = (float*)B;
    // NOTE: attT must NOT alias xBp (round-8 NaN-on-replay bug).

    prep_w_k<<<1472, 256, 0, stream>>>(W_ins, W_outs, W_ffs, W_int, W_outt, W_fft, W_tcn, wf);

    for (int n0 = 0; n0 < 64; n0 += Nc) {
        const float* xc = x + (size_t)n0 * 204800;
        float* outc     = (float*)d_out + (size_t)n0 * 204800;

        x_to_T_k<<<dim3(25, 2, Nc), 256, 0, stream>>>(xc, D, xBp);
        gemm_t_k<0><<<dim3(25, 6, Nc), 256, 0, stream>>>(D, W_ins16, b_ins, nullptr, nullptr,
                                                         nullptr, A, 128, 384);
        att_s_mfma_k<<<dim3(24 * Nc), 256, 0, stream>>>(A, P);
        att_s_fin_k<<<dim3(3 * Nc), 256, 0, stream>>>(P, alphas, att0s, attS);
        apply_s_mfma_k<<<dim3(64 * Nc), 256, 0, stream>>>(xBp, attS, A);
        fused2_k<384><<<dim3(25, 1, Nc), 256, 0, stream>>>(A, W_outs16, b_outs, g_outs, be_outs,
                                                           W_ffs16, b_ffs, g_ffs, be_ffs, D, C);
        t_to_B_k<<<dim3(Nc, 25), 256, 0, stream>>>(C, Y2B);
        gemm_t_k<0><<<dim3(25, 8, Nc), 256, 0, stream>>>(C, W_int16, b_int, nullptr, nullptr,
                                                         nullptr, A, 128, 512);
        att_t_mfma_k<<<dim3(4 * Nc), 256, 0, stream>>>(A, alphat_b, alphat_f, attT);
        apply_t_mfma_k<<<dim3(Nc, 10), 256, 0, stream>>>(Y2B, attT, A);
        fused2_k<512><<<dim3(25, 1, Nc), 256, 0, stream>>>(A, W_outt16, b_outt, g_outt, be_outt,
                                                           W_fft16, b_fft, g_fft, be_fft, C, D);
        tcn_T_k<<<dim3(25, 2, Nc), 256, 0, stream>>>(D, W_tcn16, b_tcn, g_tcn, be_tcn, A);
        T_to_out_k<<<dim3(25, 1, Nc), 256, 0, stream>>>(A, outc);
    }
}

// Round 14
// 414.615 us; speedup vs baseline: 1.0400x; 1.0269x over previous
//
#include <hip/hip_runtime.h>

#define BNSC 0.99999500003749963f

typedef _Float16 f16;
typedef _Float16 f16x8 __attribute__((ext_vector_type(8)));
typedef float    f32x4 __attribute__((ext_vector_type(4)));

static __device__ __forceinline__ float lrelu_f(float a) { return a >= 0.0f ? a : 0.1f * a; }

// XCD-locality swizzle (bijective; identity when (GX*GZ)%8 != 0).
static __device__ __forceinline__ void xcd_swz(int& bx, int& by, int& bz) {
    const int GX = gridDim.x, GY = gridDim.y, GZ = gridDim.z;
    if (((GX * GZ) & 7) == 0) {
        const int lin = blockIdx.x + GX * (blockIdx.y + GY * blockIdx.z);
        const int xcd = lin & 7;
        const int rest = lin >> 3;
        by = rest % GY;
        const int g = (rest / GY) * 8 + xcd;
        bx = g % GX;
        bz = g / GX;
    } else {
        bx = blockIdx.x; by = blockIdx.y; bz = blockIdx.z;
    }
}

// ============ weight prep: fp32 -> f16 copies (+ tcn permute (m,k,tau)->(tau,m,k)) ============
__global__ __launch_bounds__(256) void prep_w_k(
    const float* __restrict__ Wins, const float* __restrict__ Wouts,
    const float* __restrict__ Wffs, const float* __restrict__ Wint,
    const float* __restrict__ Woutt, const float* __restrict__ Wfft,
    const float* __restrict__ Wtcn, f16* __restrict__ dst)
{
    int i = blockIdx.x * 256 + threadIdx.x;
    int o = 0;
    if (i < 49152) { dst[o + i] = (f16)Wins[i];  return; } i -= 49152; o += 49152;
    if (i < 49152) { dst[o + i] = (f16)Wouts[i]; return; } i -= 49152; o += 49152;
    if (i < 16384) { dst[o + i] = (f16)Wffs[i];  return; } i -= 16384; o += 16384;
    if (i < 65536) { dst[o + i] = (f16)Wint[i];  return; } i -= 65536; o += 65536;
    if (i < 65536) { dst[o + i] = (f16)Woutt[i]; return; } i -= 65536; o += 65536;
    if (i < 16384) { dst[o + i] = (f16)Wfft[i];  return; } i -= 16384; o += 16384;
    if (i < 114688) {
        int tau = i / 16384, rem = i - tau * 16384;      // rem = m*128 + k
        dst[o + i] = (f16)Wtcn[(size_t)rem * 7 + tau];
    }
}

// ============ x (n,128,1600) fp32 -> xT (n,1600,128) f16  AND xBp (n,128,64,32) f16 ============
__global__ __launch_bounds__(256) void x_to_T_k(const float* __restrict__ x,
                                                f16* __restrict__ xT, f16* __restrict__ xBp)
{
    __shared__ float L[64 * 68];
    const int n = blockIdx.z, tv0 = blockIdx.x * 64, c0 = blockIdx.y * 64;
    const int tid = threadIdx.x;
    const int cc = tid >> 4, tv4 = (tid & 15) * 4;
    f16* xBn = xBp + (size_t)n * 262144;
    #pragma unroll
    for (int p = 0; p < 4; ++p) {
        const int c = cc + p * 16;
        float4 v = *(const float4*)&x[((size_t)n * 128 + c0 + c) * 1600 + tv0 + tv4];
        *(float4*)&L[c * 68 + tv4] = v;
        const float vv[4] = {v.x, v.y, v.z, v.w};
        #pragma unroll
        for (int e = 0; e < 4; ++e) {
            const int tvg = tv0 + tv4 + e;
            const int t = tvg / 25, u = tvg - t * 25;
            xBn[(size_t)(c0 + c) * 2048 + t * 32 + u] = (f16)vv[e];
        }
    }
    __syncthreads();
    const int tv = tid & 63, cb = (tid >> 6) * 16;
    f16x8 o0, o1;
    #pragma unroll
    for (int i = 0; i < 8; ++i) o0[i] = (f16)L[(cb + i) * 68 + tv];
    #pragma unroll
    for (int i = 0; i < 8; ++i) o1[i] = (f16)L[(cb + 8 + i) * 68 + tv];
    f16* dst = &xT[((size_t)n * 1600 + tv0 + tv) * 128 + c0 + cb];
    *(f16x8*)dst = o0;
    *(f16x8*)(dst + 8) = o1;
}

// ============ outT (n,1600,128) f16 -> out (n,128,1600) fp32 ============
__global__ __launch_bounds__(256) void T_to_out_k(const f16* __restrict__ oT, float* __restrict__ out)
{
    __shared__ float L[128 * 69];
    const int n = blockIdx.z, tv0 = blockIdx.x * 64;
    const int tid = threadIdx.x;
    #pragma unroll
    for (int p = 0; p < 4; ++p) {
        int idx = tid + p * 256;
        int tv = idx >> 4, c8 = (idx & 15) * 8;
        f16x8 v = *(const f16x8*)&oT[((size_t)n * 1600 + tv0 + tv) * 128 + c8];
        #pragma unroll
        for (int i = 0; i < 8; ++i) L[(c8 + i) * 69 + tv] = (float)v[i];
    }
    __syncthreads();
    const int c = tid >> 1, tvb = (tid & 1) * 32;
    #pragma unroll
    for (int j = 0; j < 8; ++j) {
        float4 o;
        o.x = L[c * 69 + tvb + j * 4 + 0];
        o.y = L[c * 69 + tvb + j * 4 + 1];
        o.z = L[c * 69 + tvb + j * 4 + 2];
        o.w = L[c * 69 + tvb + j * 4 + 3];
        *(float4*)&out[((size_t)n * 128 + c) * 1600 + tv0 + tvb + j * 4] = o;
    }
}

// ============ T-layout MFMA GEMM (64x64 tile, BK=128), conflict-free staging ========
template<int EPI>
__global__ __launch_bounds__(256) void gemm_t_k(
    const f16* __restrict__ A, const f16* __restrict__ W,
    const float* __restrict__ bias,
    const float* __restrict__ g, const float* __restrict__ be,
    const f16* __restrict__ res, f16* __restrict__ out,
    int K, int M)
{
    __shared__ __align__(16) char smem[34816];
    f16* As = (f16*)smem;
    f16* Bs = (f16*)(smem + 17408);
    float* Ss = (float*)smem;
    int bx, by, bz;
    xcd_swz(bx, by, bz);
    const int n = bz, tv0 = bx * 64, m0 = by * 64;
    const int tid = threadIdx.x;
    const int w = tid >> 6, lane = tid & 63;
    const int wr = w >> 1, wc = w & 1;
    const int lg = lane >> 4, lr = lane & 15;
    const int srow = tid >> 3;
    const int sc8 = (tid & 7) * 8;
    const f16* An = A + (size_t)n * 1600 * K;
    f32x4 acc[2][2] = {};

    for (int k0 = 0; k0 < K; k0 += 128) {
        const f16* ar0 = An + (size_t)(tv0 + srow) * K + k0;
        const f16* ar1 = An + (size_t)(tv0 + srow + 32) * K + k0;
        const f16* br0 = W + (size_t)(m0 + srow) * K + k0;
        const f16* br1 = W + (size_t)(m0 + srow + 32) * K + k0;
        uint4 a00 = *(const uint4*)(ar0 + sc8),      a01 = *(const uint4*)(ar0 + 64 + sc8);
        uint4 a10 = *(const uint4*)(ar1 + sc8),      a11 = *(const uint4*)(ar1 + 64 + sc8);
        uint4 b00 = *(const uint4*)(br0 + sc8),      b01 = *(const uint4*)(br0 + 64 + sc8);
        uint4 b10 = *(const uint4*)(br1 + sc8),      b11 = *(const uint4*)(br1 + 64 + sc8);
        __syncthreads();
        *(uint4*)&As[srow * 136 + sc8]             = a00;
        *(uint4*)&As[srow * 136 + 64 + sc8]        = a01;
        *(uint4*)&As[(srow + 32) * 136 + sc8]      = a10;
        *(uint4*)&As[(srow + 32) * 136 + 64 + sc8] = a11;
        *(uint4*)&Bs[srow * 136 + sc8]             = b00;
        *(uint4*)&Bs[srow * 136 + 64 + sc8]        = b01;
        *(uint4*)&Bs[(srow + 32) * 136 + sc8]      = b10;
        *(uint4*)&Bs[(srow + 32) * 136 + 64 + sc8] = b11;
        __syncthreads();
        #pragma unroll
        for (int kb = 0; kb < 128; kb += 32) {
            f16x8 af0 = *(const f16x8*)&As[(wr * 32 + lr) * 136 + kb + lg * 8];
            f16x8 af1 = *(const f16x8*)&As[(wr * 32 + 16 + lr) * 136 + kb + lg * 8];
            f16x8 bf0 = *(const f16x8*)&Bs[(wc * 32 + lr) * 136 + kb + lg * 8];
            f16x8 bf1 = *(const f16x8*)&Bs[(wc * 32 + 16 + lr) * 136 + kb + lg * 8];
            acc[0][0] = __builtin_amdgcn_mfma_f32_16x16x32_f16(af0, bf0, acc[0][0], 0, 0, 0);
            acc[0][1] = __builtin_amdgcn_mfma_f32_16x16x32_f16(af0, bf1, acc[0][1], 0, 0, 0);
            acc[1][0] = __builtin_amdgcn_mfma_f32_16x16x32_f16(af1, bf0, acc[1][0], 0, 0, 0);
            acc[1][1] = __builtin_amdgcn_mfma_f32_16x16x32_f16(af1, bf1, acc[1][1], 0, 0, 0);
        }
        __syncthreads();
    }
    #pragma unroll
    for (int fi = 0; fi < 2; ++fi)
        #pragma unroll
        for (int fj = 0; fj < 2; ++fj)
            #pragma unroll
            for (int rr = 0; rr < 4; ++rr)
                Ss[(wr * 32 + fi * 16 + lg * 4 + rr) * 68 + wc * 32 + fj * 16 + lr] = acc[fi][fj][rr];
    __syncthreads();
    const int tvl = tid >> 2, mq = (tid & 3) * 16;
    const int tv = tv0 + tvl;
    const int m  = m0 + mq;
    float vals[16];
    #pragma unroll
    for (int j = 0; j < 4; ++j)
        *(float4*)&vals[j * 4] = *(const float4*)&Ss[tvl * 68 + mq + j * 4];
    float bi[16];
    #pragma unroll
    for (int j = 0; j < 4; ++j) *(float4*)&bi[j * 4] = *(const float4*)&bias[m + j * 4];
    if (EPI == 1) {
        float gg[16], bb[16];
        #pragma unroll
        for (int j = 0; j < 4; ++j) {
            *(float4*)&gg[j * 4] = *(const float4*)&g[m + j * 4];
            *(float4*)&bb[j * 4] = *(const float4*)&be[m + j * 4];
        }
        const f16* rp = res + ((size_t)n * 1600 + tv) * M + m;
        f16x8 r0 = *(const f16x8*)rp;
        f16x8 r1 = *(const f16x8*)(rp + 8);
        #pragma unroll
        for (int j = 0; j < 16; ++j) {
            float r = (float)((j < 8) ? r0[j & 7] : r1[j & 7]);
            vals[j] = lrelu_f(r + (vals[j] + bi[j]) * (gg[j] * BNSC) + bb[j]);
        }
    } else {
        #pragma unroll
        for (int j = 0; j < 16; ++j) vals[j] += bi[j];
    }
    f16x8 o0, o1;
    #pragma unroll
    for (int j = 0; j < 8; ++j) { o0[j] = (f16)vals[j]; o1[j] = (f16)vals[8 + j]; }
    f16* op = out + ((size_t)n * 1600 + tv) * M + m;
    *(f16x8*)op = o0;
    *(f16x8*)(op + 8) = o1;
}

// ============ FUSED dual GEMM (32-row tile): out = epi2(W2 @ epi1(W1 @ Ain)) ============
// 32-row tv tiles (1600 = 50x32): 3200 blocks, LDS peak 27.1 KB -> 6 blocks/CU, ~4% tail.
template<int K1>
__global__ __launch_bounds__(256) void fused2_k(
    const f16* __restrict__ Ain,   // (64,1600,K1)
    const f16* __restrict__ W1,    // (128,K1)
    const float* __restrict__ b1, const float* __restrict__ g1, const float* __restrict__ be1,
    const f16* __restrict__ W2,    // (128,128)
    const float* __restrict__ b2, const float* __restrict__ g2, const float* __restrict__ be2,
    const f16* __restrict__ res,   // (64,1600,128)
    f16* __restrict__ out)         // (64,1600,128)
{
    __shared__ __align__(16) char smem[27648];
    f16* As1  = (f16*)smem;                 // 32 x 72  = 4608 B
    f16* Bs1  = (f16*)(smem + 4608);        // 128 x 72 = 18432 B (end 23040)
    float* Ss = (float*)smem;               // 32 x 132 f32 = 16896 B
    f16* Ys   = (f16*)smem;                 // 32 x 136 = 8704 B
    f16* Bs2  = (f16*)(smem + 8704);        // 128 x 72 = 18432 B (end 27136)
    int bx, by, bz;
    xcd_swz(bx, by, bz);
    const int n = bz, tv0 = bx * 32;
    const int tid = threadIdx.x;
    const int w = tid >> 6, lane = tid & 63;
    const int wr = w >> 1, wc = w & 1;           // wave rows: wr*16; wave cols: wc*64
    const int lg = lane >> 4, lr = lane & 15;
    const int srow = tid >> 3, sc = (tid & 7) * 8;
    const f16* An = Ain + (size_t)n * 1600 * K1;
    const f16* rn = res + ((size_t)n * 1600 + tv0) * 128;

    // ---- phase 1: 32x128 tile of gemm1 over K1 (BK=64) ----
    f32x4 acc[4] = {};
    for (int k0 = 0; k0 < K1; k0 += 64) {
        uint4 a0  = *(const uint4*)(An + (size_t)(tv0 + srow) * K1 + k0 + sc);
        uint4 w0  = *(const uint4*)(W1 + (size_t)srow * K1 + k0 + sc);
        uint4 w1v = *(const uint4*)(W1 + (size_t)(srow + 32) * K1 + k0 + sc);
        uint4 w2v = *(const uint4*)(W1 + (size_t)(srow + 64) * K1 + k0 + sc);
        uint4 w3v = *(const uint4*)(W1 + (size_t)(srow + 96) * K1 + k0 + sc);
        __syncthreads();
        *(uint4*)&As1[srow * 72 + sc] = a0;
        *(uint4*)&Bs1[srow * 72 + sc] = w0;
        *(uint4*)&Bs1[(srow + 32) * 72 + sc] = w1v;
        *(uint4*)&Bs1[(srow + 64) * 72 + sc] = w2v;
        *(uint4*)&Bs1[(srow + 96) * 72 + sc] = w3v;
        __syncthreads();
        #pragma unroll
        for (int kb = 0; kb < 64; kb += 32) {
            f16x8 af = *(const f16x8*)&As1[(wr * 16 + lr) * 72 + kb + lg * 8];
            #pragma unroll
            for (int ft = 0; ft < 4; ++ft) {
                f16x8 bf = *(const f16x8*)&Bs1[(wc * 64 + ft * 16 + lr) * 72 + kb + lg * 8];
                acc[ft] = __builtin_amdgcn_mfma_f32_16x16x32_f16(af, bf, acc[ft], 0, 0, 0);
            }
        }
        __syncthreads();
    }
    // ---- epilogue 1 -> Ys (LDS only) ----
    #pragma unroll
    for (int ft = 0; ft < 4; ++ft)
        #pragma unroll
        for (int rr = 0; rr < 4; ++rr)
            Ss[(wr * 16 + lg * 4 + rr) * 132 + wc * 64 + ft * 16 + lr] = acc[ft][rr];
    __syncthreads();
    const int tvl = tid >> 3, mq = (tid & 7) * 16;    // 32 rows x 8 col-chunks
    f16x8 yh0, yh1;
    {
        float vals[16], bb[16], gg[16], eb[16];
        #pragma unroll
        for (int j = 0; j < 4; ++j) {
            *(float4*)&vals[j * 4] = *(const float4*)&Ss[tvl * 132 + mq + j * 4];
            *(float4*)&bb[j * 4]   = *(const float4*)&b1[mq + j * 4];
            *(float4*)&gg[j * 4]   = *(const float4*)&g1[mq + j * 4];
            *(float4*)&eb[j * 4]   = *(const float4*)&be1[mq + j * 4];
        }
        const f16* rp = rn + (size_t)tvl * 128 + mq;
        f16x8 r0 = *(const f16x8*)rp, r1 = *(const f16x8*)(rp + 8);
        #pragma unroll
        for (int j = 0; j < 16; ++j) {
            float r = (float)((j < 8) ? r0[j & 7] : r1[j & 7]);
            vals[j] = lrelu_f(r + (vals[j] + bb[j]) * (gg[j] * BNSC) + eb[j]);
        }
        #pragma unroll
        for (int j = 0; j < 8; ++j) { yh0[j] = (f16)vals[j]; yh1[j] = (f16)vals[8 + j]; }
    }
    __syncthreads();   // all Ss reads done before Ys (alias) writes
    *(f16x8*)&Ys[tvl * 136 + mq]     = yh0;
    *(f16x8*)&Ys[tvl * 136 + mq + 8] = yh1;

    // ---- phase 2: gemm2 (K=128, BK=64), A = Ys ----
    f32x4 acc2[4] = {};
    for (int k2 = 0; k2 < 128; k2 += 64) {
        uint4 w0  = *(const uint4*)(W2 + (size_t)srow * 128 + k2 + sc);
        uint4 w1v = *(const uint4*)(W2 + (size_t)(srow + 32) * 128 + k2 + sc);
        uint4 w2v = *(const uint4*)(W2 + (size_t)(srow + 64) * 128 + k2 + sc);
        uint4 w3v = *(const uint4*)(W2 + (size_t)(srow + 96) * 128 + k2 + sc);
        __syncthreads();   // orders Ys writes (iter0) / prior MFMA Bs2 reads (iter1) before Bs2 writes
        *(uint4*)&Bs2[srow * 72 + sc] = w0;
        *(uint4*)&Bs2[(srow + 32) * 72 + sc] = w1v;
        *(uint4*)&Bs2[(srow + 64) * 72 + sc] = w2v;
        *(uint4*)&Bs2[(srow + 96) * 72 + sc] = w3v;
        __syncthreads();
        #pragma unroll
        for (int kb = 0; kb < 64; kb += 32) {
            f16x8 af = *(const f16x8*)&Ys[(wr * 16 + lr) * 136 + k2 + kb + lg * 8];
            #pragma unroll
            for (int ft = 0; ft < 4; ++ft) {
                f16x8 bf = *(const f16x8*)&Bs2[(wc * 64 + ft * 16 + lr) * 72 + kb + lg * 8];
                acc2[ft] = __builtin_amdgcn_mfma_f32_16x16x32_f16(af, bf, acc2[ft], 0, 0, 0);
            }
        }
    }
    __syncthreads();
    // ---- epilogue 2 -> global out ----
    #pragma unroll
    for (int ft = 0; ft < 4; ++ft)
        #pragma unroll
        for (int rr = 0; rr < 4; ++rr)
            Ss[(wr * 16 + lg * 4 + rr) * 132 + wc * 64 + ft * 16 + lr] = acc2[ft][rr];
    __syncthreads();
    {
        float vals[16], bb[16], gg[16], eb[16];
        #pragma unroll
        for (int j = 0; j < 4; ++j) {
            *(float4*)&vals[j * 4] = *(const float4*)&Ss[tvl * 132 + mq + j * 4];
            *(float4*)&bb[j * 4]   = *(const float4*)&b2[mq + j * 4];
            *(float4*)&gg[j * 4]   = *(const float4*)&g2[mq + j * 4];
            *(float4*)&eb[j * 4]   = *(const float4*)&be2[mq + j * 4];
        }
        const f16* rp = rn + (size_t)tvl * 128 + mq;
        f16x8 r0 = *(const f16x8*)rp, r1 = *(const f16x8*)(rp + 8);
        #pragma unroll
        for (int j = 0; j < 16; ++j) {
            float r = (float)((j < 8) ? r0[j & 7] : r1[j & 7]);
            vals[j] = lrelu_f(r + (vals[j] + bb[j]) * (gg[j] * BNSC) + eb[j]);
        }
        f16x8 o0, o1;
        #pragma unroll
        for (int j = 0; j < 8; ++j) { o0[j] = (f16)vals[j]; o1[j] = (f16)vals[8 + j]; }
        f16* op = out + ((size_t)n * 1600 + tv0 + tvl) * 128 + mq;
        *(f16x8*)op = o0;
        *(f16x8*)(op + 8) = o1;
    }
}

// ============ TCN (64x64 tile, BK=128 per tau), conflict-free staging ============
__global__ __launch_bounds__(256) void tcn_T_k(
    const f16* __restrict__ z2T, const f16* __restrict__ W7,
    const float* __restrict__ bias, const float* __restrict__ g,
    const float* __restrict__ be, f16* __restrict__ outT)
{
    __shared__ __align__(16) char smem[34816];
    f16* As = (f16*)smem;
    f16* Bs = (f16*)(smem + 17408);
    float* Ss = (float*)smem;
    int bx, by, bz;
    xcd_swz(bx, by, bz);
    const int n = bz, tv0 = bx * 64, m0 = by * 64;
    const int tid = threadIdx.x;
    const int w = tid >> 6, lane = tid & 63;
    const int wr = w >> 1, wc = w & 1;
    const int lg = lane >> 4, lr = lane & 15;
    const int srow = tid >> 3;
    const int sc8 = (tid & 7) * 8;
    const f16* Zn = z2T + (size_t)n * 204800;
    f32x4 acc[2][2] = {};

    for (int tau = 0; tau < 7; ++tau) {
        const int shift = (tau - 3) * 25;
        const f16* Wt = W7 + tau * 16384;
        const int gr0 = tv0 + srow + shift;
        const int gr1 = gr0 + 32;
        uint4 a00 = make_uint4(0,0,0,0), a01 = a00, a10 = a00, a11 = a00;
        if (gr0 >= 0 && gr0 < 1600) {
            const f16* p = Zn + (size_t)gr0 * 128;
            a00 = *(const uint4*)(p + sc8); a01 = *(const uint4*)(p + 64 + sc8);
        }
        if (gr1 >= 0 && gr1 < 1600) {
            const f16* p = Zn + (size_t)gr1 * 128;
            a10 = *(const uint4*)(p + sc8); a11 = *(const uint4*)(p + 64 + sc8);
        }
        const f16* br0 = Wt + (size_t)(m0 + srow) * 128;
        const f16* br1 = Wt + (size_t)(m0 + srow + 32) * 128;
        uint4 b00 = *(const uint4*)(br0 + sc8), b01 = *(const uint4*)(br0 + 64 + sc8);
        uint4 b10 = *(const uint4*)(br1 + sc8), b11 = *(const uint4*)(br1 + 64 + sc8);
        __syncthreads();
        *(uint4*)&As[srow * 136 + sc8]             = a00;
        *(uint4*)&As[srow * 136 + 64 + sc8]        = a01;
        *(uint4*)&As[(srow + 32) * 136 + sc8]      = a10;
        *(uint4*)&As[(srow + 32) * 136 + 64 + sc8] = a11;
        *(uint4*)&Bs[srow * 136 + sc8]             = b00;
        *(uint4*)&Bs[srow * 136 + 64 + sc8]        = b01;
        *(uint4*)&Bs[(srow + 32) * 136 + sc8]      = b10;
        *(uint4*)&Bs[(srow + 32) * 136 + 64 + sc8] = b11;
        __syncthreads();
        #pragma unroll
        for (int kb = 0; kb < 128; kb += 32) {
            f16x8 af0 = *(const f16x8*)&As[(wr * 32 + lr) * 136 + kb + lg * 8];
            f16x8 af1 = *(const f16x8*)&As[(wr * 32 + 16 + lr) * 136 + kb + lg * 8];
            f16x8 bf0 = *(const f16x8*)&Bs[(wc * 32 + lr) * 136 + kb + lg * 8];
            f16x8 bf1 = *(const f16x8*)&Bs[(wc * 32 + 16 + lr) * 136 + kb + lg * 8];
            acc[0][0] = __builtin_amdgcn_mfma_f32_16x16x32_f16(af0, bf0, acc[0][0], 0, 0, 0);
            acc[0][1] = __builtin_amdgcn_mfma_f32_16x16x32_f16(af0, bf1, acc[0][1], 0, 0, 0);
            acc[1][0] = __builtin_amdgcn_mfma_f32_16x16x32_f16(af1, bf0, acc[1][0], 0, 0, 0);
            acc[1][1] = __builtin_amdgcn_mfma_f32_16x16x32_f16(af1, bf1, acc[1][1], 0, 0, 0);
        }
        __syncthreads();
    }
    #pragma unroll
    for (int fi = 0; fi < 2; ++fi)
        #pragma unroll
        for (int fj = 0; fj < 2; ++fj)
            #pragma unroll
            for (int rr = 0; rr < 4; ++rr)
                Ss[(wr * 32 + fi * 16 + lg * 4 + rr) * 68 + wc * 32 + fj * 16 + lr] = acc[fi][fj][rr];
    __syncthreads();
    const int tvl = tid >> 2, mq = (tid & 3) * 16;
    const int tv = tv0 + tvl;
    const int m  = m0 + mq;
    float vals[16], bi[16], gg[16], bb[16];
    #pragma unroll
    for (int j = 0; j < 4; ++j) {
        *(float4*)&vals[j * 4] = *(const float4*)&Ss[tvl * 68 + mq + j * 4];
        *(float4*)&bi[j * 4]   = *(const float4*)&bias[m + j * 4];
        *(float4*)&gg[j * 4]   = *(const float4*)&g[m + j * 4];
        *(float4*)&bb[j * 4]   = *(const float4*)&be[m + j * 4];
    }
    const f16* rp = Zn + (size_t)tv * 128 + m;
    f16x8 r0 = *(const f16x8*)rp;
    f16x8 r1 = *(const f16x8*)(rp + 8);
    #pragma unroll
    for (int j = 0; j < 16; ++j) {
        float r = (float)((j < 8) ? r0[j & 7] : r1[j & 7]);
        vals[j] = lrelu_f(r + (vals[j] + bi[j]) * (gg[j] * BNSC) + bb[j]);
    }
    f16x8 o0, o1;
    #pragma unroll
    for (int j = 0; j < 8; ++j) { o0[j] = (f16)vals[j]; o1[j] = (f16)vals[8 + j]; }
    f16* op = outT + ((size_t)n * 1600 + tv) * 128 + m;
    *(f16x8*)op = o0;
    *(f16x8*)(op + 8) = o1;
}

// ============ spatial scores via MFMA, t-chunked partials ============
__global__ __launch_bounds__(256) void att_s_mfma_k(
    const f16* __restrict__ QKT, float* __restrict__ P)
{
    __shared__ float Lred[4][1024];
    const int n = blockIdx.x / 24;
    const int rs = blockIdx.x % 24;
    const int s = rs >> 3, tc = rs & 7;
    const int tid = threadIdx.x;
    const int w = tid >> 6, lane = tid & 63;
    const int lg = lane >> 4, lr = lane & 15;
    const int qc = s * 64, kc = 192 + s * 64;
    const f16* Qn = QKT + (size_t)n * 1600 * 384;
    f32x4 acc[2][2] = {};

    #pragma unroll
    for (int tt = 0; tt < 2; ++tt) {
        const int t = tc * 8 + w * 2 + tt;
        const size_t rbase = (size_t)t * 25;
        #pragma unroll
        for (int kb = 0; kb < 2; ++kb) {
            f16x8 a[2] = {}, b[2] = {};
            #pragma unroll
            for (int rt = 0; rt < 2; ++rt) {
                const int u = rt * 16 + lr;
                if (u < 25) {
                    const f16* rp = Qn + (rbase + u) * 384;
                    a[rt] = *(const f16x8*)(rp + qc + kb * 32 + lg * 8);
                    b[rt] = *(const f16x8*)(rp + kc + kb * 32 + lg * 8);
                }
            }
            #pragma unroll
            for (int rt = 0; rt < 2; ++rt)
                #pragma unroll
                for (int ct = 0; ct < 2; ++ct)
                    acc[rt][ct] = __builtin_amdgcn_mfma_f32_16x16x32_f16(a[rt], b[ct], acc[rt][ct], 0, 0, 0);
        }
    }
    #pragma unroll
    for (int rt = 0; rt < 2; ++rt)
        #pragma unroll
        for (int ct = 0; ct < 2; ++ct)
            #pragma unroll
            for (int rr = 0; rr < 4; ++rr) {
                const int u = rt * 16 + lg * 4 + rr;
                const int v = ct * 16 + lr;
                Lred[w][u * 32 + v] = acc[rt][ct][rr];
            }
    __syncthreads();
    float* Pp = P + (((size_t)n * 3 + s) * 8 + tc) * 1024;
    for (int i = tid; i < 1024; i += 256)
        Pp[i] = Lred[0][i] + Lred[1][i] + Lred[2][i] + Lred[3][i];
}

// finalize: att[n,s,u,v] = tanh(sum_tc P /4096)*alpha + att0
__global__ __launch_bounds__(256) void att_s_fin_k(
    const float* __restrict__ P, const float* __restrict__ alphas,
    const float* __restrict__ att0s, float* __restrict__ att)
{
    const int n = blockIdx.x / 3, s = blockIdx.x % 3;
    const float* Pp = P + ((size_t)n * 3 + s) * 8192;
    const float al = alphas[s];
    for (int p = threadIdx.x; p < 625; p += 256) {
        const int u = p / 25, v = p - u * 25;
        float sum = 0.f;
        #pragma unroll
        for (int tc = 0; tc < 8; ++tc) sum += Pp[tc * 1024 + u * 32 + v];
        att[((size_t)n * 3 + s) * 625 + p] = tanhf(sum * (1.0f / 4096.0f)) * al + att0s[s * 625 + p];
    }
}

// ============ temporal scores via MFMA + fused tanh/mask epilogue ============
__global__ __launch_bounds__(256) void att_t_mfma_k(
    const f16* __restrict__ QKT,
    const float* __restrict__ alphat_b, const float* __restrict__ alphat_f,
    float* __restrict__ att)
{
    __shared__ f16 Qs[64 * 72];
    __shared__ f16 Ks[64 * 72];
    const int n = blockIdx.x >> 2, r = blockIdx.x & 3;
    const int br = r >> 1, s = r & 1;
    const int qg = ((br == 0) ? s : 2 + s) * 64;
    const int kg = ((br == 0) ? 4 + s : 6 + s) * 64;
    const f16* Qn = QKT + (size_t)n * 1600 * 512;
    const int tid = threadIdx.x;
    const int w = tid >> 6, lane = tid & 63;
    const int lg = lane >> 4, lr = lane & 15;
    const int srow = tid >> 2, scol = (tid & 3) * 16;
    f32x4 acc[4] = {};

    for (int v = 0; v < 25; ++v) {
        const f16* rowp = Qn + (size_t)(srow * 25 + v) * 512;
        uint4 q0 = *(const uint4*)(rowp + qg + scol);
        uint4 q1 = *(const uint4*)(rowp + qg + scol + 8);
        uint4 k0 = *(const uint4*)(rowp + kg + scol);
        uint4 k1 = *(const uint4*)(rowp + kg + scol + 8);
        __syncthreads();
        *(uint4*)&Qs[srow * 72 + scol] = q0;
        *(uint4*)&Qs[srow * 72 + scol + 8] = q1;
        *(uint4*)&Ks[srow * 72 + scol] = k0;
        *(uint4*)&Ks[srow * 72 + scol + 8] = k1;
        __syncthreads();
        #pragma unroll
        for (int kb = 0; kb < 2; ++kb) {
            f16x8 a = *(const f16x8*)&Qs[(w * 16 + lr) * 72 + kb * 32 + lg * 8];
            #pragma unroll
            for (int ct = 0; ct < 4; ++ct) {
                f16x8 b = *(const f16x8*)&Ks[(ct * 16 + lr) * 72 + kb * 32 + lg * 8];
                acc[ct] = __builtin_amdgcn_mfma_f32_16x16x32_f16(a, b, acc[ct], 0, 0, 0);
            }
        }
    }
    const float al = (br == 0) ? alphat_f[s] : alphat_b[s];
    float* ap = att + (((size_t)n * 2 + br) * 2 + s) * 4096;
    #pragma unroll
    for (int ct = 0; ct < 4; ++ct) {
        #pragma unroll
        for (int rr = 0; rr < 4; ++rr) {
            const int t = w * 16 + lg * 4 + rr;
            const int q = ct * 16 + lr;
            const bool keep = (br == 0) ? (t >= q) : (q >= t);
            ap[t * 64 + q] = keep ? tanhf(acc[ct][rr] * (1.0f / 1600.0f)) * al : 0.0f;
        }
    }
}

// ============ apply spatial att via MFMA ============
__global__ __launch_bounds__(256) void apply_s_mfma_k(
    const f16* __restrict__ xBp, const float* __restrict__ att, f16* __restrict__ y1T)
{
    __shared__ f16 As[3 * 32 * 48];
    const int n = blockIdx.x >> 6, t = blockIdx.x & 63;
    const int tid = threadIdx.x;
    const int w = tid >> 6, lane = tid & 63;
    const int lg = lane >> 4, lr = lane & 15;
    const float* an = att + (size_t)n * 1875;
    for (int i = tid; i < 3 * 32 * 48; i += 256) {
        int s = i / 1536, r2 = i - s * 1536;
        int v = r2 / 48, u = r2 - v * 48;
        As[i] = (v < 25 && u < 25) ? (f16)an[s * 625 + u * 25 + v] : (f16)0.f;
    }
    __syncthreads();
    const f16* Bn = xBp + (size_t)n * 262144 + (size_t)t * 32;
    f16x8 bf[2];
    #pragma unroll
    for (int ct = 0; ct < 2; ++ct)
        bf[ct] = *(const f16x8*)(Bn + (size_t)(w * 32 + ct * 16 + lr) * 2048 + lg * 8);
    #pragma unroll
    for (int s = 0; s < 3; ++s) {
        f32x4 acc[2][2] = {};
        #pragma unroll
        for (int vt = 0; vt < 2; ++vt) {
            f16x8 a = *(const f16x8*)&As[s * 1536 + (vt * 16 + lr) * 48 + lg * 8];
            #pragma unroll
            for (int ct = 0; ct < 2; ++ct)
                acc[vt][ct] = __builtin_amdgcn_mfma_f32_16x16x32_f16(a, bf[ct], acc[vt][ct], 0, 0, 0);
        }
        #pragma unroll
        for (int vt = 0; vt < 2; ++vt)
            #pragma unroll
            for (int ct = 0; ct < 2; ++ct)
                #pragma unroll
                for (int rr = 0; rr < 4; ++rr) {
                    const int v = vt * 16 + lg * 4 + rr;
                    if (v < 25) {
                        const int c = w * 32 + ct * 16 + lr;
                        y1T[((size_t)n * 1600 + t * 25 + v) * 384 + s * 128 + c] = (f16)acc[vt][ct][rr];
                    }
                }
    }
}

// ============ y2T (Nc,1600,128) -> Y2B (Nc,25,128,64) [v][c][t] ============
__global__ __launch_bounds__(256) void t_to_B_k(
    const f16* __restrict__ y2T, f16* __restrict__ Y2B)
{
    __shared__ f16 L[64 * 136];
    const int n = blockIdx.x, v = blockIdx.y;
    const f16* Yn = y2T + (size_t)n * 204800;
    const int tid = threadIdx.x;
    for (int i = tid; i < 1024; i += 256) {
        int t = i >> 4, c8 = (i & 15) * 8;
        *(f16x8*)&L[t * 136 + c8] = *(const f16x8*)&Yn[(size_t)(t * 25 + v) * 128 + c8];
    }
    __syncthreads();
    const int c = tid >> 1, t0 = (tid & 1) * 32;
    f16* dst = Y2B + ((size_t)n * 25 + v) * 8192 + (size_t)c * 64 + t0;
    #pragma unroll
    for (int j = 0; j < 4; ++j) {
        f16x8 o;
        #pragma unroll
        for (int e = 0; e < 8; ++e) o[e] = L[(t0 + j * 8 + e) * 136 + c];
        *(f16x8*)(dst + j * 8) = o;
    }
}

// ============ apply temporal att via MFMA — one block serves all 4 r (wave w = r) ============
__global__ __launch_bounds__(256) void apply_t_mfma_k(
    const f16* __restrict__ Y2B, const float* __restrict__ att, f16* __restrict__ zT)
{
    __shared__ f16 AsT[4][64 * 72];
    const int n = blockIdx.x;
    const int by = blockIdx.y;
    const int vg = by >> 1;
    const int ch = (by & 1) * 64;
    const int tid = threadIdx.x;
    const int w = tid >> 6, lane = tid & 63;
    const int lg = lane >> 4, lr = lane & 15;
    const float* ap = att + (size_t)n * 4 * 4096;
    for (int i = tid; i < 4 * 4096; i += 256) {
        int r = i >> 12, rem = i & 4095;
        int t = rem >> 6, q = rem & 63;
        AsT[r][q * 72 + t] = (f16)ap[i];
    }
    __syncthreads();
    f16x8 af[4][2];
    #pragma unroll
    for (int qt = 0; qt < 4; ++qt)
        #pragma unroll
        for (int kb = 0; kb < 2; ++kb)
            af[qt][kb] = *(const f16x8*)&AsT[w][(qt * 16 + lr) * 72 + kb * 32 + lg * 8];

    for (int vi = 0; vi < 5; ++vi) {
        const int v = vg * 5 + vi;
        const f16* Bv = Y2B + ((size_t)n * 25 + v) * 8192 + (size_t)ch * 64;
        f32x4 acc[4][4] = {};
        #pragma unroll
        for (int kb = 0; kb < 2; ++kb)
            #pragma unroll
            for (int ct = 0; ct < 4; ++ct) {
                f16x8 bf = *(const f16x8*)(Bv + (size_t)(ct * 16 + lr) * 64 + kb * 32 + lg * 8);
                #pragma unroll
                for (int qt = 0; qt < 4; ++qt)
                    acc[qt][ct] = __builtin_amdgcn_mfma_f32_16x16x32_f16(af[qt][kb], bf, acc[qt][ct], 0, 0, 0);
            }
        #pragma unroll
        for (int qt = 0; qt < 4; ++qt)
            #pragma unroll
            for (int ct = 0; ct < 4; ++ct)
                #pragma unroll
                for (int rr = 0; rr < 4; ++rr) {
                    const int q = qt * 16 + lg * 4 + rr;
                    const int c = ch + ct * 16 + lr;
                    zT[((size_t)n * 1600 + q * 25 + v) * 512 + w * 128 + c] = (f16)acc[qt][ct][rr];
                }
    }
}

extern "C" void kernel_launch(void* const* d_in, const int* in_sizes, int n_in,
                              void* d_out, int out_size, void* d_ws, size_t ws_size,
                              hipStream_t stream) {
    const float* x       = (const float*)d_in[0];
    const float* W_ins   = (const float*)d_in[1];
    const float* b_ins   = (const float*)d_in[2];
    const float* alphas  = (const float*)d_in[3];
    const float* att0s   = (const float*)d_in[4];
    const float* W_outs  = (const float*)d_in[5];
    const float* b_outs  = (const float*)d_in[6];
    const float* g_outs  = (const float*)d_in[7];
    const float* be_outs = (const float*)d_in[8];
    const float* W_ffs   = (const float*)d_in[9];
    const float* b_ffs   = (const float*)d_in[10];
    const float* g_ffs   = (const float*)d_in[11];
    const float* be_ffs  = (const float*)d_in[12];
    const float* W_int   = (const float*)d_in[13];
    const float* b_int   = (const float*)d_in[14];
    const float* alphat_b= (const float*)d_in[15];
    const float* alphat_f= (const float*)d_in[16];
    const float* W_outt  = (const float*)d_in[17];
    const float* b_outt  = (const float*)d_in[18];
    const float* g_outt  = (const float*)d_in[19];
    const float* be_outt = (const float*)d_in[20];
    const float* W_fft   = (const float*)d_in[21];
    const float* b_fft   = (const float*)d_in[22];
    const float* g_fft   = (const float*)d_in[23];
    const float* be_fft  = (const float*)d_in[24];
    const float* W_tcn   = (const float*)d_in[25];
    const float* b_tcn   = (const float*)d_in[26];
    const float* g_tcn   = (const float*)d_in[27];
    const float* be_tcn  = (const float*)d_in[28];

    // ---- weights (f16) at workspace head ----
    f16* wf = (f16*)d_ws;
    f16* W_ins16  = wf;            // 49152
    f16* W_outs16 = wf + 49152;    // 49152
    f16* W_ffs16  = wf + 98304;    // 16384
    f16* W_int16  = wf + 114688;   // 65536
    f16* W_outt16 = wf + 180224;   // 65536
    f16* W_fft16  = wf + 245760;   // 16384
    f16* W_tcn16  = wf + 262144;   // 114688  -> end 376832 f16 = 753664 B
    const size_t wbytes = 753664;

    // per-n f16: A 819200, B/C/D 204800, Y2B 204800, xBp 262144
    const size_t perN = (819200ull + 3ull * 204800ull + 204800ull + 262144ull) * 2ull;
    int Nc = 64;
    while (Nc > 4 && wbytes + (size_t)Nc * perN > ws_size) Nc >>= 1;

    f16* A   = (f16*)((char*)d_ws + wbytes);
    f16* B   = A   + (size_t)Nc * 819200;
    f16* C   = B   + (size_t)Nc * 204800;
    f16* D   = C   + (size_t)Nc * 204800;   // xT, later z2
    f16* Y2B = D   + (size_t)Nc * 204800;
    f16* xBp = Y2B + (size_t)Nc * 204800;
    float* P    = (float*)Y2B;
    float* attS = (float*)Y2B + (size_t)Nc * 24576;
    float* attT = (float*)B;
    // NOTE: attT must NOT alias xBp (round-8 NaN-on-replay bug).

    prep_w_k<<<1472, 256, 0, stream>>>(W_ins, W_outs, W_ffs, W_int, W_outt, W_fft, W_tcn, wf);

    for (int n0 = 0; n0 < 64; n0 += Nc) {
        const float* xc = x + (size_t)n0 * 204800;
        float* outc     = (float*)d_out + (size_t)n0 * 204800;

        x_to_T_k<<<dim3(25, 2, Nc), 256, 0, stream>>>(xc, D, xBp);
        gemm_t_k<0><<<dim3(25, 6, Nc), 256, 0, stream>>>(D, W_ins16, b_ins, nullptr, nullptr,
                                                         nullptr, A, 128, 384);
        att_s_mfma_k<<<dim3(24 * Nc), 256, 0, stream>>>(A, P);
        att_s_fin_k<<<dim3(3 * Nc), 256, 0, stream>>>(P, alphas, att0s, attS);
        apply_s_mfma_k<<<dim3(64 * Nc), 256, 0, stream>>>(xBp, attS, A);
        fused2_k<384><<<dim3(50, 1, Nc), 256, 0, stream>>>(A, W_outs16, b_outs, g_outs, be_outs,
                                                           W_ffs16, b_ffs, g_ffs, be_ffs, D, C);
        t_to_B_k<<<dim3(Nc, 25), 256, 0, stream>>>(C, Y2B);
        gemm_t_k<0><<<dim3(25, 8, Nc), 256, 0, stream>>>(C, W_int16, b_int, nullptr, nullptr,
                                                         nullptr, A, 128, 512);
        att_t_mfma_k<<<dim3(4 * Nc), 256, 0, stream>>>(A, alphat_b, alphat_f, attT);
        apply_t_mfma_k<<<dim3(Nc, 10), 256, 0, stream>>>(Y2B, attT, A);
        fused2_k<512><<<dim3(50, 1, Nc), 256, 0, stream>>>(A, W_outt16, b_outt, g_outt, be_outt,
                                                           W_fft16, b_fft, g_fft, be_fft, C, D);
        tcn_T_k<<<dim3(25, 2, Nc), 256, 0, stream>>>(D, W_tcn16, b_tcn, g_tcn, be_tcn, A);
        T_to_out_k<<<dim3(25, 1, Nc), 256, 0, stream>>>(A, outc);
    }
}